// Round 2
// baseline (3032.969 us; speedup 1.0000x reference)
//
#include <hip/hip_runtime.h>
#include <math.h>

#define Bq 8
#define Tq 4096
#define Dq 512
#define Qn 4
#define Kk 1024
#define OWn 2048
#define NROWS (Bq*Tq)
#define CHUNK 16384
#define CAP 256

#define QO_OFF (Bq*OWn*Dq)
#define IDX_OFF (QO_OFF + Bq*Tq*Dq)
#define LOSS_OFF (IDX_OFF + Qn*NROWS)

typedef __bf16 bf16x8 __attribute__((ext_vector_type(8)));
typedef __bf16 bf16x4 __attribute__((ext_vector_type(4)));
typedef float f32x16 __attribute__((ext_vector_type(16)));
typedef float f32x4 __attribute__((ext_vector_type(4)));

// ---------------- prep: codebook norms + bf16 codebook + zero loss ----------------
__global__ __launch_bounds__(256) void prep_kernel(const float* __restrict__ cb,
                                                   float* __restrict__ cbnorm,
                                                   __bf16* __restrict__ cbh,
                                                   float* __restrict__ lacc) {
  int w = threadIdx.x >> 6, lane = threadIdx.x & 63;
  int row = blockIdx.x * 4 + w;                   // 0..4095
  const f32x4* c4 = (const f32x4*)(cb + (size_t)row * Dq);
  f32x4 v0 = c4[lane * 2], v1 = c4[lane * 2 + 1];
  float s = v0.x*v0.x + v0.y*v0.y + v0.z*v0.z + v0.w*v0.w
          + v1.x*v1.x + v1.y*v1.y + v1.z*v1.z + v1.w*v1.w;
  bf16x8 bv;
  bv[0]=(__bf16)v0.x; bv[1]=(__bf16)v0.y; bv[2]=(__bf16)v0.z; bv[3]=(__bf16)v0.w;
  bv[4]=(__bf16)v1.x; bv[5]=(__bf16)v1.y; bv[6]=(__bf16)v1.z; bv[7]=(__bf16)v1.w;
  *(bf16x8*)(cbh + (size_t)row * Dq + lane * 8) = bv;
#pragma unroll
  for (int off = 32; off; off >>= 1) s += __shfl_down(s, off);
  if (lane == 0) cbnorm[row] = s;
  if (blockIdx.x == 0 && threadIdx.x == 0) *lacc = 0.f;
}

__global__ __launch_bounds__(256) void prep2_kernel(const float* __restrict__ cbnorm,
                                                    float* __restrict__ cmax) {
  int w = threadIdx.x >> 6, lane = threadIdx.x & 63;
  float m = 0.f;
#pragma unroll
  for (int j = 0; j < 16; ++j) m = fmaxf(m, cbnorm[w * Kk + lane * 16 + j]);
#pragma unroll
  for (int off = 32; off; off >>= 1) m = fmaxf(m, __shfl_down(m, off));
  if (lane == 0) cmax[w] = sqrtf(m);
}

// ---------------- screening GEMM: S~ = ||c||^2 - 2*(rh . ch), bf16 MFMA ----------------
// 512 threads = 8 waves; BM=64 rows/block; grid 256 (one 16384-row chunk)
__global__ __launch_bounds__(512, 1) void vq_screen(const float* __restrict__ x,
                                                    const float* __restrict__ qo,
                                                    const __bf16* __restrict__ cbh_q,
                                                    const float* __restrict__ cbnorm_q,
                                                    __bf16* __restrict__ S,
                                                    float* __restrict__ rnorm,
                                                    int chunkBase, int first) {
  __shared__ __bf16 rh[64 * 512];   // 64KB, XOR-swizzled rows
  const int tid = threadIdx.x;
  const int srow = tid >> 3, sc = tid & 7;      // staging: row 0..63, col-group 0..7
  const int row0g = chunkBase + blockIdx.x * 64;

  // ---- stage residual tile as bf16 (+ per-row ||r||^2) ----
  float rnp = 0.f;
  {
    char* rhc = (char*)rh;
    const int swz = (srow & 7) << 4;
    size_t grow = (size_t)(row0g + srow) * Dq;
#pragma unroll
    for (int i = 0; i < 16; ++i) {
      int d0 = i * 32 + sc * 4;
      f32x4 xv = *(const f32x4*)(x + grow + d0);
      f32x4 rv;
      if (first) rv = xv;
      else {
        f32x4 qv = *(const f32x4*)(qo + grow + d0);
        rv.x = xv.x - qv.x; rv.y = xv.y - qv.y; rv.z = xv.z - qv.z; rv.w = xv.w - qv.w;
      }
      rnp += rv.x*rv.x + rv.y*rv.y + rv.z*rv.z + rv.w*rv.w;
      bf16x4 bv;
      bv[0]=(__bf16)rv.x; bv[1]=(__bf16)rv.y; bv[2]=(__bf16)rv.z; bv[3]=(__bf16)rv.w;
      *(bf16x4*)(rhc + ((srow * 1024 + d0 * 2) ^ swz)) = bv;
    }
    rnp += __shfl_down(rnp, 4, 8);
    rnp += __shfl_down(rnp, 2, 8);
    rnp += __shfl_down(rnp, 1, 8);
    if (sc == 0) rnorm[row0g + srow] = rnp;
  }
  __syncthreads();

  // ---- MFMA main ----
  const int w = tid >> 6, lane = tid & 63;
  const int l31 = lane & 31, hs = lane >> 5;
  const int rowgrp = (w >> 2) * 32;
  const int kq = (w & 3) * 256;
  const int arow = rowgrp + l31;
  const int abase = arow * 1024 + hs * 16;
  const int aswz = (arow & 7) << 4;
  const char* rhc = (const char*)rh;
  const int lrow0 = blockIdx.x * 64 + rowgrp;

  for (int ct = 0; ct < 8; ++ct) {
    const int bcol = kq + ct * 32 + l31;
    const __bf16* bp = cbh_q + ((size_t)bcol << 9) + (hs << 3);
    f32x16 acc;
#pragma unroll
    for (int i = 0; i < 16; ++i) acc[i] = 0.f;
#pragma unroll 4
    for (int ds = 0; ds < 32; ++ds) {
      bf16x8 a = *(const bf16x8*)(rhc + ((abase + ds * 32) ^ aswz));
      bf16x8 b = *(const bf16x8*)(bp + ds * 16);
      acc = __builtin_amdgcn_mfma_f32_32x32x16_bf16(a, b, acc, 0, 0, 0);
    }
    const float cn = cbnorm_q[bcol];
#pragma unroll
    for (int i = 0; i < 16; ++i) {
      int rit = (i & 3) + 8 * (i >> 2) + 4 * hs;
      float s = cn - 2.f * acc[i];
      S[((size_t)(lrow0 + rit) << 10) + bcol] = (__bf16)s;
    }
  }
}

// ---------------- select: exact argmin via certified rescore, then update ----------------
// 256 threads = 4 waves, 1 row per wave; grid 4096 per chunk
__global__ __launch_bounds__(256) void vq_select(const float* __restrict__ x,
                                                 float* __restrict__ qo,
                                                 const float* __restrict__ cb_q,
                                                 const float* __restrict__ cbnorm_q,
                                                 const float* __restrict__ cmax_q,
                                                 const __bf16* __restrict__ S,
                                                 const float* __restrict__ rnorm,
                                                 float* __restrict__ idx_q,
                                                 float* __restrict__ lacc,
                                                 int chunkBase, int first) {
  __shared__ int clist[4 * CAP];
  __shared__ int wcount[4];
  const int tid = threadIdx.x;
  const int w = tid >> 6, lane = tid & 63;
  const int lrow = blockIdx.x * 4 + w;
  const int grow = chunkBase + lrow;

  // load scores (16 per lane, k = lane*16+j)
  const bf16x8* sp = (const bf16x8*)(S + ((size_t)lrow << 10));
  bf16x8 sa = sp[lane * 2], sb = sp[lane * 2 + 1];
  float sf[16];
#pragma unroll
  for (int j = 0; j < 8; ++j) { sf[j] = (float)sa[j]; sf[8 + j] = (float)sb[j]; }

  // wave min of screening scores
  float m1 = 3.4028235e38f;
#pragma unroll
  for (int j = 0; j < 16; ++j) m1 = fminf(m1, sf[j]);
#pragma unroll
  for (int off = 1; off < 64; off <<= 1) m1 = fminf(m1, __shfl_xor(m1, off));

  // residual row (8 f32 per lane, in regs)
  size_t gb = (size_t)grow * Dq + lane * 8;
  f32x4 x0 = *(const f32x4*)(x + gb), x1 = *(const f32x4*)(x + gb + 4);
  f32x4 q0, q1, r0, r1;
  if (first) { r0 = x0; r1 = x1; }
  else {
    q0 = *(const f32x4*)(qo + gb); q1 = *(const f32x4*)(qo + gb + 4);
    r0.x=x0.x-q0.x; r0.y=x0.y-q0.y; r0.z=x0.z-q0.z; r0.w=x0.w-q0.w;
    r1.x=x1.x-q1.x; r1.y=x1.y-q1.y; r1.z=x1.z-q1.z; r1.w=x1.w-q1.w;
  }

  // certified threshold
  float rn = sqrtf(rnorm[grow]);
  float cm = *cmax_q;
  float delta = 0.04f * rn * cm + 0.008f * (cm * cm + 2.f * rn * cm);
  float thr = m1 + delta;

  // gather candidates
  if (lane == 0) wcount[w] = 0;
#pragma unroll
  for (int j = 0; j < 16; ++j) {
    if (sf[j] <= thr) {
      int pos = atomicAdd(&wcount[w], 1);
      if (pos < CAP) clist[w * CAP + pos] = lane * 16 + j;
    }
  }
  int cnt = wcount[w];

  // cooperative exact f32 rescore of each candidate
  float bs = 3.4028235e38f; int bk = 1 << 30;
  int total = (cnt > CAP) ? Kk : cnt;
  for (int ci = 0; ci < total; ++ci) {
    int k = (cnt > CAP) ? ci : clist[w * CAP + ci];
    const f32x4* crow = (const f32x4*)(cb_q + ((size_t)k << 9)) + lane * 2;
    f32x4 c0 = crow[0], c1 = crow[1];
    float dot = 0.f;
    dot = fmaf(r0.x, c0.x, dot); dot = fmaf(r0.y, c0.y, dot);
    dot = fmaf(r0.z, c0.z, dot); dot = fmaf(r0.w, c0.w, dot);
    dot = fmaf(r1.x, c1.x, dot); dot = fmaf(r1.y, c1.y, dot);
    dot = fmaf(r1.z, c1.z, dot); dot = fmaf(r1.w, c1.w, dot);
#pragma unroll
    for (int off = 1; off < 64; off <<= 1) dot += __shfl_xor(dot, off);
    float sc = cbnorm_q[k] - 2.f * dot;
    if (sc < bs || (sc == bs && k < bk)) { bs = sc; bk = k; }
  }

  if (lane == 0) idx_q[grow] = (float)bk;

  // update: qo += cb[bk]; loss += ||r - cb[bk]||^2
  const f32x4* crow = (const f32x4*)(cb_q + ((size_t)bk << 9)) + lane * 2;
  f32x4 c0 = crow[0], c1 = crow[1];
  f32x4 n0, n1;
  if (first) { n0 = c0; n1 = c1; }
  else {
    n0.x=q0.x+c0.x; n0.y=q0.y+c0.y; n0.z=q0.z+c0.z; n0.w=q0.w+c0.w;
    n1.x=q1.x+c1.x; n1.y=q1.y+c1.y; n1.z=q1.z+c1.z; n1.w=q1.w+c1.w;
  }
  *(f32x4*)(qo + gb) = n0; *(f32x4*)(qo + gb + 4) = n1;
  float a0=r0.x-c0.x, a1=r0.y-c0.y, a2=r0.z-c0.z, a3=r0.w-c0.w;
  float a4=r1.x-c1.x, a5=r1.y-c1.y, a6=r1.z-c1.z, a7=r1.w-c1.w;
  float lp = a0*a0+a1*a1+a2*a2+a3*a3+a4*a4+a5*a5+a6*a6+a7*a7;
#pragma unroll
  for (int off = 32; off; off >>= 1) lp += __shfl_down(lp, off);
  if (lane == 0) atomicAdd(lacc, lp);
}

// ---------------- conv1d stride2 SAME + exact GELU (unchanged) ----------------
__global__ __launch_bounds__(256) void conv_gelu(const float* __restrict__ qo,
                                                 const float* __restrict__ w,
                                                 float* __restrict__ y) {
  __shared__ float A[132 * 20];
  __shared__ float Wt[5 * 16 * 64];
  const int tid = threadIdx.x;
  const int r = tid >> 4, c = tid & 15;
  const int co0 = blockIdx.x * 64, o0 = blockIdx.y * 64, n = blockIdx.z;

  float acc[4][4];
#pragma unroll
  for (int m = 0; m < 4; ++m)
#pragma unroll
    for (int j = 0; j < 4; ++j) acc[m][j] = 0.f;

  for (int dt = 0; dt < 32; ++dt) {
    __syncthreads();
    for (int s = tid; s < 524; s += 256) {
      int row = s >> 2, c4 = s & 3;
      int gi = 2 * o0 - 1 + row;
      float4 v = {0.f, 0.f, 0.f, 0.f};
      if (gi >= 0 && gi < Tq)
        v = *(const float4*)(qo + (size_t)(n * Tq + gi) * Dq + dt * 16 + c4 * 4);
      *(float4*)(A + row * 20 + c4 * 4) = v;
    }
#pragma unroll
    for (int i = 0; i < 5; ++i) {
      int s = i * 256 + tid;
      int kw = s >> 8, rest = s & 255, ci = rest >> 4, c4 = rest & 15;
      float4 v = *(const float4*)(w + (size_t)(kw * Dq + dt * 16 + ci) * Dq + co0 + c4 * 4);
      *(float4*)(Wt + (kw * 16 + ci) * 64 + c4 * 4) = v;
    }
    __syncthreads();
#pragma unroll 4
    for (int ci = 0; ci < 16; ++ci) {
      float4 wv[5];
#pragma unroll
      for (int kw = 0; kw < 5; ++kw)
        wv[kw] = *(float4*)(Wt + (kw * 16 + ci) * 64 + c * 4);
#pragma unroll
      for (int m = 0; m < 4; ++m) {
        int p2 = 2 * (r + 16 * m);
#pragma unroll
        for (int kw = 0; kw < 5; ++kw) {
          float a = A[(p2 + kw) * 20 + ci];
          acc[m][0] = fmaf(a, wv[kw].x, acc[m][0]);
          acc[m][1] = fmaf(a, wv[kw].y, acc[m][1]);
          acc[m][2] = fmaf(a, wv[kw].z, acc[m][2]);
          acc[m][3] = fmaf(a, wv[kw].w, acc[m][3]);
        }
      }
    }
  }
#pragma unroll
  for (int m = 0; m < 4; ++m) {
    int p = o0 + r + 16 * m;
    float4 g;
    g.x = 0.5f * acc[m][0] * (1.f + erff(acc[m][0] * 0.70710678118654752f));
    g.y = 0.5f * acc[m][1] * (1.f + erff(acc[m][1] * 0.70710678118654752f));
    g.z = 0.5f * acc[m][2] * (1.f + erff(acc[m][2] * 0.70710678118654752f));
    g.w = 0.5f * acc[m][3] * (1.f + erff(acc[m][3] * 0.70710678118654752f));
    *(float4*)(y + (size_t)(n * OWn + p) * Dq + co0 + c * 4) = g;
  }
}

__global__ void loss_final(const float* __restrict__ lacc, float* __restrict__ out) {
  out[0] = 0.25f * lacc[0] / 16777216.0f;
}

extern "C" void kernel_launch(void* const* d_in, const int* in_sizes, int n_in,
                              void* d_out, int out_size, void* d_ws, size_t ws_size,
                              hipStream_t stream) {
  const float* x  = (const float*)d_in[0];
  const float* cb = (const float*)d_in[1];
  const float* w  = (const float*)d_in[2];
  float* out = (float*)d_out;
  float* y    = out;
  float* qo   = out + QO_OFF;
  float* idxo = out + IDX_OFF;
  float* losso = out + LOSS_OFF;

  float* fws    = (float*)d_ws;
  float* cbnorm = fws;             // 4096
  float* cmax   = fws + 4096;      // 4
  float* lacc   = fws + 4100;      // 1
  float* rnorm  = fws + 4104;      // 32768
  __bf16* cbh   = (__bf16*)((char*)d_ws + (256 << 10));                    // 4 MB
  __bf16* Sbuf  = (__bf16*)((char*)d_ws + (256 << 10) + (4 << 20));        // 32 MB

  prep_kernel<<<1024, 256, 0, stream>>>(cb, cbnorm, cbh, lacc);
  prep2_kernel<<<1, 256, 0, stream>>>(cbnorm, cmax);

  for (int qi = 0; qi < Qn; ++qi) {
    for (int ch = 0; ch < 2; ++ch) {
      vq_screen<<<256, 512, 0, stream>>>(x, qo, cbh + (size_t)qi * Kk * Dq,
                                         cbnorm + qi * Kk, Sbuf, rnorm,
                                         ch * CHUNK, qi == 0);
      vq_select<<<4096, 256, 0, stream>>>(x, qo, cb + (size_t)qi * Kk * Dq,
                                          cbnorm + qi * Kk, cmax + qi, Sbuf, rnorm,
                                          idxo + (size_t)qi * NROWS, lacc,
                                          ch * CHUNK, qi == 0);
    }
  }
  conv_gelu<<<dim3(8, 32, 8), 256, 0, stream>>>(qo, w, y);
  loss_final<<<1, 1, 0, stream>>>(lacc, losso);
}

// Round 3
// 892.881 us; speedup vs baseline: 3.3968x; 3.3968x over previous
//
#include <hip/hip_runtime.h>
#include <math.h>

#define Bq 8
#define Tq 4096
#define Dq 512
#define Qn 4
#define Kk 1024
#define OWn 2048
#define NROWS (Bq*Tq)
#define CHUNK 16384

#define QO_OFF (Bq*OWn*Dq)
#define IDX_OFF (QO_OFF + Bq*Tq*Dq)
#define LOSS_OFF (IDX_OFF + Qn*NROWS)

typedef __bf16 bf16x8 __attribute__((ext_vector_type(8)));
typedef __bf16 bf16x4 __attribute__((ext_vector_type(4)));
typedef float f32x16 __attribute__((ext_vector_type(16)));
typedef float f32x4 __attribute__((ext_vector_type(4)));

// ============ prep: codebook norms + fragment-ready bf16 codebook ============
// grid 1024 x 256: wave per codebook row (4096 rows total)
__global__ __launch_bounds__(256) void prep_cb(const float* __restrict__ cb,
                                               float* __restrict__ cbnorm,
                                               __bf16* __restrict__ cbf,
                                               float* __restrict__ lacc) {
  int w = threadIdx.x >> 6, lane = threadIdx.x & 63;
  int row = blockIdx.x * 4 + w;                 // 0..4095 = q*1024 + k
  int q = row >> 10, k = row & 1023;
  const f32x4* c4 = (const f32x4*)(cb + (size_t)row * Dq);
  f32x4 v0 = c4[lane * 2], v1 = c4[lane * 2 + 1];
  float s = v0.x*v0.x + v0.y*v0.y + v0.z*v0.z + v0.w*v0.w
          + v1.x*v1.x + v1.y*v1.y + v1.z*v1.z + v1.w*v1.w;
  bf16x8 bv;
  bv[0]=(__bf16)v0.x; bv[1]=(__bf16)v0.y; bv[2]=(__bf16)v0.z; bv[3]=(__bf16)v0.w;
  bv[4]=(__bf16)v1.x; bv[5]=(__bf16)v1.y; bv[6]=(__bf16)v1.z; bv[7]=(__bf16)v1.w;
  // fragment layout: [blk=k>>5][ds=lane>>1][hs=lane&1][l31=k&31][8]
  int ds = lane >> 1, hs = lane & 1;
  size_t off = ((size_t)((k >> 5) * 32 + ds) * 2 + hs) * 256 + (k & 31) * 8;
  *(bf16x8*)(cbf + (size_t)q * (Kk * Dq) + off) = bv;
#pragma unroll
  for (int off2 = 32; off2; off2 >>= 1) s += __shfl_down(s, off2);
  if (lane == 0) cbnorm[row] = s;
  if (blockIdx.x == 0 && threadIdx.x == 0) *lacc = 0.f;
}

__global__ __launch_bounds__(256) void prep_cmax(const float* __restrict__ cbnorm,
                                                 float* __restrict__ cmax) {
  int w = threadIdx.x >> 6, lane = threadIdx.x & 63;
  float m = 0.f;
#pragma unroll
  for (int j = 0; j < 16; ++j) m = fmaxf(m, cbnorm[w * Kk + lane * 16 + j]);
#pragma unroll
  for (int off = 32; off; off >>= 1) m = fmaxf(m, __shfl_down(m, off));
  if (lane == 0) cmax[w] = sqrtf(m);
}

// ============ prep: fragment-ready bf16 conv weights ============
// layout: [s=kw*32+ci16][c32][hs][l31][8]; grid 640 x 256
__global__ __launch_bounds__(256) void prep_wb(const float* __restrict__ w,
                                               __bf16* __restrict__ wb) {
  int g = blockIdx.x * 256 + threadIdx.x;       // 0..163839
  int l31 = g & 31, hs = (g >> 5) & 1, c32 = (g >> 6) & 15, s = g >> 10;
  int kw = s >> 5, ci16 = s & 31;
  int ci = ci16 * 16 + hs * 8;
  int co = c32 * 32 + l31;
  bf16x8 bv;
#pragma unroll
  for (int e = 0; e < 8; ++e)
    bv[e] = (__bf16)w[(size_t)(kw * Dq + ci + e) * Dq + co];
  *(bf16x8*)(wb + (size_t)g * 8) = bv;
}

// ============ fused VQ step: bf16-MFMA screen + certified rescore + update ====
// block: 512 thr = 8 waves; 64 rows x 1024 codes; grid 256 per 16384-row chunk
__global__ __launch_bounds__(512, 2) void vq_fused(
    const float* __restrict__ x, float* __restrict__ qo,
    const __bf16* __restrict__ cbf_q, const float* __restrict__ cb_q,
    const float* __restrict__ cbnorm_q, const float* __restrict__ cmax_q,
    __bf16* __restrict__ S, float* __restrict__ idx_q, float* __restrict__ lacc,
    int chunkBase, int first) {
  __shared__ __bf16 rh[64 * 512];               // 64KB swizzled residual
  __shared__ float rnorm_l[64];
  __shared__ unsigned int redB[64 * 8];
  __shared__ float thrL[64];
  __shared__ int rowcount[64];
  __shared__ unsigned short rowlist[64 * 32];

  const int tid = threadIdx.x;
  const int lrow0 = blockIdx.x * 64;            // row within chunk
  const int row0g = chunkBase + lrow0;          // global row

  // ---- stage residual bf16 tile + per-row ||r||^2 ----
  {
    const int srow = tid >> 3, sc = tid & 7;
    char* rhc = (char*)rh;
    const int swz = (srow & 7) << 4;
    size_t grow = (size_t)(row0g + srow) * Dq;
    float rnp = 0.f;
#pragma unroll
    for (int i = 0; i < 16; ++i) {
      int d0 = i * 32 + sc * 4;
      f32x4 xv = *(const f32x4*)(x + grow + d0);
      f32x4 rv;
      if (first) rv = xv;
      else {
        f32x4 qv = *(const f32x4*)(qo + grow + d0);
        rv.x = xv.x - qv.x; rv.y = xv.y - qv.y; rv.z = xv.z - qv.z; rv.w = xv.w - qv.w;
      }
      rnp += rv.x*rv.x + rv.y*rv.y + rv.z*rv.z + rv.w*rv.w;
      bf16x4 bv;
      bv[0]=(__bf16)rv.x; bv[1]=(__bf16)rv.y; bv[2]=(__bf16)rv.z; bv[3]=(__bf16)rv.w;
      *(bf16x4*)(rhc + ((srow * 1024 + d0 * 2) ^ swz)) = bv;
    }
    rnp += __shfl_down(rnp, 4, 8);
    rnp += __shfl_down(rnp, 2, 8);
    rnp += __shfl_down(rnp, 1, 8);
    if (sc == 0) rnorm_l[srow] = rnp;
  }
  __syncthreads();

  // ---- screen: wave w owns cols [w*128, w*128+128), rows 0..63 (2 rowtiles) --
  const int w = tid >> 6, lane = tid & 63, l31 = lane & 31, hs = lane >> 5;
  const char* rhc = (const char*)rh;
  unsigned int best0[16], best1[16];
#pragma unroll
  for (int i = 0; i < 16; ++i) { best0[i] = 0xFFFFFFFFu; best1[i] = 0xFFFFFFFFu; }

  const int ab0 = l31 * 1024 + hs * 16;
  const int ab1 = ab0 + 32 * 1024;
  const int asw = (l31 & 7) << 4;

  for (int ct = 0; ct < 4; ++ct) {
    const int col = w * 128 + ct * 32 + l31;
    const int blk = w * 4 + ct;
    const __bf16* bp = cbf_q + (size_t)blk * 16384 + hs * 256 + l31 * 8;
    f32x16 acc0, acc1;
#pragma unroll
    for (int i = 0; i < 16; ++i) { acc0[i] = 0.f; acc1[i] = 0.f; }
#pragma unroll 8
    for (int ds = 0; ds < 32; ++ds) {
      bf16x8 b  = *(const bf16x8*)(bp + ds * 512);
      bf16x8 a0 = *(const bf16x8*)(rhc + ((ab0 + ds * 32) ^ asw));
      bf16x8 a1 = *(const bf16x8*)(rhc + ((ab1 + ds * 32) ^ asw));
      acc0 = __builtin_amdgcn_mfma_f32_32x32x16_bf16(a0, b, acc0, 0, 0, 0);
      acc1 = __builtin_amdgcn_mfma_f32_32x32x16_bf16(a1, b, acc1, 0, 0, 0);
    }
    const float cn = cbnorm_q[col];
#pragma unroll
    for (int i = 0; i < 16; ++i) {
      int rit = (i & 3) + 8 * (i >> 2) + 4 * hs;
      {
        float s = cn - 2.f * acc0[i];
        __bf16 h = (__bf16)s;
        S[((size_t)(lrow0 + rit) << 10) + col] = h;
        unsigned short ub = __builtin_bit_cast(unsigned short, h);
        unsigned short key = (ub & 0x8000) ? (unsigned short)(ub ^ 0xFFFF)
                                           : (unsigned short)(ub | 0x8000);
        unsigned pk = ((unsigned)key << 10) | (unsigned)col;
        if (pk < best0[i]) best0[i] = pk;
      }
      {
        float s = cn - 2.f * acc1[i];
        __bf16 h = (__bf16)s;
        S[((size_t)(lrow0 + 32 + rit) << 10) + col] = h;
        unsigned short ub = __builtin_bit_cast(unsigned short, h);
        unsigned short key = (ub & 0x8000) ? (unsigned short)(ub ^ 0xFFFF)
                                           : (unsigned short)(ub | 0x8000);
        unsigned pk = ((unsigned)key << 10) | (unsigned)col;
        if (pk < best1[i]) best1[i] = pk;
      }
    }
  }
  // cross-lane umin over the 32 cols held per half-wave
#pragma unroll
  for (int i = 0; i < 16; ++i) {
#pragma unroll
    for (int off = 1; off <= 16; off <<= 1) {
      unsigned t0 = __shfl_xor(best0[i], off);
      if (t0 < best0[i]) best0[i] = t0;
      unsigned t1 = __shfl_xor(best1[i], off);
      if (t1 < best1[i]) best1[i] = t1;
    }
  }
  if (l31 == 0) {
#pragma unroll
    for (int i = 0; i < 16; ++i) {
      int rit = (i & 3) + 8 * (i >> 2) + 4 * hs;
      redB[rit * 8 + w] = best0[i];
      redB[(32 + rit) * 8 + w] = best1[i];
    }
  }
  __syncthreads();

  // ---- per-row min across 8 waves -> certified threshold ----
  if (tid < 64) {
    unsigned mb = redB[tid * 8];
#pragma unroll
    for (int j = 1; j < 8; ++j) {
      unsigned v = redB[tid * 8 + j];
      if (v < mb) mb = v;
    }
    unsigned key = (mb >> 10) & 0xFFFF;
    unsigned ub = (key & 0x8000) ? (key ^ 0x8000) : (key ^ 0xFFFF);
    float mstar = __uint_as_float(ub << 16);
    float rn = sqrtf(rnorm_l[tid]);
    float cm = *cmax_q;
    thrL[tid] = mstar + 0.025f * rn * cm + 0.0045f * cm * cm;
    rowcount[tid] = 0;
  }
  __syncthreads();

  // ---- candidate scan: wave w owns rows w*8 .. w*8+7 ----
  for (int rr = 0; rr < 8; ++rr) {
    int row = w * 8 + rr;
    float thr = thrL[row];
    const __bf16* sp = S + ((size_t)(lrow0 + row) << 10) + lane * 16;
    bf16x8 s0 = *(const bf16x8*)(sp);
    bf16x8 s1 = *(const bf16x8*)(sp + 8);
#pragma unroll
    for (int j = 0; j < 8; ++j) {
      if ((float)s0[j] <= thr) {
        int p = atomicAdd(&rowcount[row], 1);
        if (p < 32) rowlist[row * 32 + p] = (unsigned short)(lane * 16 + j);
      }
      if ((float)s1[j] <= thr) {
        int p = atomicAdd(&rowcount[row], 1);
        if (p < 32) rowlist[row * 32 + p] = (unsigned short)(lane * 16 + 8 + j);
      }
    }
  }
  __syncthreads();

  // ---- exact f32 rescore + update (wave w: rows w*8..w*8+7) ----
  float lsum = 0.f;
  for (int rr = 0; rr < 8; ++rr) {
    int row = w * 8 + rr;
    int grow2 = row0g + row;
    size_t gb = (size_t)grow2 * Dq + lane * 8;
    f32x4 x0 = *(const f32x4*)(x + gb), x1 = *(const f32x4*)(x + gb + 4);
    f32x4 q0, q1, r0, r1;
    if (first) { r0 = x0; r1 = x1; }
    else {
      q0 = *(const f32x4*)(qo + gb); q1 = *(const f32x4*)(qo + gb + 4);
      r0.x=x0.x-q0.x; r0.y=x0.y-q0.y; r0.z=x0.z-q0.z; r0.w=x0.w-q0.w;
      r1.x=x1.x-q1.x; r1.y=x1.y-q1.y; r1.z=x1.z-q1.z; r1.w=x1.w-q1.w;
    }
    int cnt = rowcount[row];
    int total = (cnt > 32) ? Kk : cnt;
    float bs = 3.4028235e38f; int bk = 1 << 30;
    for (int ci2 = 0; ci2 < total; ++ci2) {
      int k = (cnt > 32) ? ci2 : (int)rowlist[row * 32 + ci2];
      const f32x4* crow = (const f32x4*)(cb_q + ((size_t)k << 9)) + lane * 2;
      f32x4 c0 = crow[0], c1 = crow[1];
      float dot = 0.f;
      dot = fmaf(r0.x, c0.x, dot); dot = fmaf(r0.y, c0.y, dot);
      dot = fmaf(r0.z, c0.z, dot); dot = fmaf(r0.w, c0.w, dot);
      dot = fmaf(r1.x, c1.x, dot); dot = fmaf(r1.y, c1.y, dot);
      dot = fmaf(r1.z, c1.z, dot); dot = fmaf(r1.w, c1.w, dot);
#pragma unroll
      for (int off = 1; off < 64; off <<= 1) dot += __shfl_xor(dot, off);
      float sc = cbnorm_q[k] - 2.f * dot;
      if (sc < bs || (sc == bs && k < bk)) { bs = sc; bk = k; }
    }
    if (lane == 0) idx_q[grow2] = (float)bk;
    const f32x4* crow = (const f32x4*)(cb_q + ((size_t)bk << 9)) + lane * 2;
    f32x4 c0 = crow[0], c1 = crow[1];
    f32x4 n0, n1;
    if (first) { n0 = c0; n1 = c1; }
    else {
      n0.x=q0.x+c0.x; n0.y=q0.y+c0.y; n0.z=q0.z+c0.z; n0.w=q0.w+c0.w;
      n1.x=q1.x+c1.x; n1.y=q1.y+c1.y; n1.z=q1.z+c1.z; n1.w=q1.w+c1.w;
    }
    *(f32x4*)(qo + gb) = n0; *(f32x4*)(qo + gb + 4) = n1;
    float a0=r0.x-c0.x, a1=r0.y-c0.y, a2=r0.z-c0.z, a3=r0.w-c0.w;
    float a4=r1.x-c1.x, a5=r1.y-c1.y, a6=r1.z-c1.z, a7=r1.w-c1.w;
    lsum += a0*a0+a1*a1+a2*a2+a3*a3+a4*a4+a5*a5+a6*a6+a7*a7;
  }
#pragma unroll
  for (int off = 1; off < 64; off <<= 1) lsum += __shfl_xor(lsum, off);
  if (lane == 0) atomicAdd(lacc, lsum);
}

// ============ conv1d stride2 SAME via bf16 MFMA + exact GELU ============
// grid (128 rowblocks, 2 co-halves) x 512 thr; block = 128 outputs x 256 co
__global__ __launch_bounds__(512, 2) void conv_mfma(const float* __restrict__ qo,
                                                    const __bf16* __restrict__ wb,
                                                    float* __restrict__ y) {
  __shared__ char As[259 * 128];                // 259 input rows x 64 ci bf16
  const int tid = threadIdx.x;
  const int w = tid >> 6, lane = tid & 63, l31 = lane & 31, hs = lane >> 5;
  const int rowblk = blockIdx.x, coblk = blockIdx.y;
  const int n = rowblk >> 4;
  const int o0 = (rowblk & 15) * 128;
  const int t0 = 2 * o0 - 1;
  const int c32g = coblk * 8 + w;               // wave's 32-co tile

  f32x16 acc[4];
#pragma unroll
  for (int rt = 0; rt < 4; ++rt)
#pragma unroll
    for (int i = 0; i < 16; ++i) acc[rt][i] = 0.f;

  for (int ct8 = 0; ct8 < 8; ++ct8) {
    __syncthreads();
    for (int s = tid; s < 2072; s += 512) {
      int irow = s >> 3, cg = s & 7;
      int t = t0 + irow;
      bf16x8 bv;
      if (t >= 0 && t < Tq) {
        const float* src = qo + ((size_t)(n * Tq + t)) * Dq + ct8 * 64 + cg * 8;
        f32x4 v0 = *(const f32x4*)(src), v1 = *(const f32x4*)(src + 4);
        bv[0]=(__bf16)v0.x; bv[1]=(__bf16)v0.y; bv[2]=(__bf16)v0.z; bv[3]=(__bf16)v0.w;
        bv[4]=(__bf16)v1.x; bv[5]=(__bf16)v1.y; bv[6]=(__bf16)v1.z; bv[7]=(__bf16)v1.w;
      } else {
#pragma unroll
        for (int e = 0; e < 8; ++e) bv[e] = (__bf16)0.f;
      }
      *(bf16x8*)(As + ((irow * 128 + cg * 16) ^ (((irow >> 1) & 7) << 4))) = bv;
    }
    __syncthreads();
#pragma unroll
    for (int kw = 0; kw < 5; ++kw) {
#pragma unroll
      for (int ks = 0; ks < 4; ++ks) {
        int s16 = kw * 32 + ct8 * 4 + ks;
        bf16x8 b = *(const bf16x8*)(wb + ((size_t)(s16 * 16 + c32g) * 2 + hs) * 256 + l31 * 8);
#pragma unroll
        for (int rt = 0; rt < 4; ++rt) {
          int ir = 2 * (rt * 32 + l31) + kw;
          bf16x8 a = *(const bf16x8*)(As + ((ir * 128 + ks * 32 + hs * 16) ^ (((ir >> 1) & 7) << 4)));
          acc[rt] = __builtin_amdgcn_mfma_f32_32x32x16_bf16(a, b, acc[rt], 0, 0, 0);
        }
      }
    }
  }
  const int co = coblk * 256 + w * 32 + l31;
#pragma unroll
  for (int rt = 0; rt < 4; ++rt)
#pragma unroll
    for (int i = 0; i < 16; ++i) {
      int orow = rt * 32 + (i & 3) + 8 * (i >> 2) + 4 * hs;
      float v = acc[rt][i];
      float g = 0.5f * v * (1.f + erff(v * 0.70710678118654752f));
      y[((size_t)(n * OWn + o0 + orow)) * Dq + co] = g;
    }
}

__global__ void loss_final(const float* __restrict__ lacc, float* __restrict__ out) {
  out[0] = 0.25f * lacc[0] / 16777216.0f;
}

extern "C" void kernel_launch(void* const* d_in, const int* in_sizes, int n_in,
                              void* d_out, int out_size, void* d_ws, size_t ws_size,
                              hipStream_t stream) {
  const float* x  = (const float*)d_in[0];
  const float* cb = (const float*)d_in[1];
  const float* cw = (const float*)d_in[2];
  float* out = (float*)d_out;
  float* y    = out;
  float* qo   = out + QO_OFF;
  float* idxo = out + IDX_OFF;
  float* losso = out + LOSS_OFF;

  float* fws    = (float*)d_ws;
  float* lacc   = fws;                // 1
  float* cmax   = fws + 8;            // 4
  float* cbnorm = fws + 16;           // 4096
  __bf16* cbf = (__bf16*)((char*)d_ws + (32 << 10));        // 4 MB
  __bf16* wb  = (__bf16*)((char*)d_ws + (8 << 20));         // 2.62 MB
  __bf16* Sbuf = (__bf16*)d_out;      // y region reused as 32MB scratch

  prep_cb<<<1024, 256, 0, stream>>>(cb, cbnorm, cbf, lacc);
  prep_cmax<<<1, 256, 0, stream>>>(cbnorm, cmax);
  prep_wb<<<640, 256, 0, stream>>>(cw, wb);

  for (int qi = 0; qi < Qn; ++qi)
    for (int ch = 0; ch < 2; ++ch)
      vq_fused<<<256, 512, 0, stream>>>(x, qo,
                                        cbf + (size_t)qi * Kk * Dq,
                                        cb + (size_t)qi * Kk * Dq,
                                        cbnorm + qi * Kk, cmax + qi,
                                        Sbuf, idxo + (size_t)qi * NROWS, lacc,
                                        ch * CHUNK, qi == 0);

  conv_mfma<<<dim3(128, 2), 512, 0, stream>>>(qo, wb, y);
  loss_final<<<1, 1, 0, stream>>>(lacc, losso);
}

// Round 4
// 645.112 us; speedup vs baseline: 4.7015x; 1.3841x over previous
//
#include <hip/hip_runtime.h>
#include <math.h>

#define Bq 8
#define Tq 4096
#define Dq 512
#define Qn 4
#define Kk 1024
#define OWn 2048
#define NROWS (Bq*Tq)

#define QO_OFF (Bq*OWn*Dq)
#define IDX_OFF (QO_OFF + Bq*Tq*Dq)
#define LOSS_OFF (IDX_OFF + Qn*NROWS)

typedef __bf16 bf16x8 __attribute__((ext_vector_type(8)));
typedef __bf16 bf16x4 __attribute__((ext_vector_type(4)));
typedef float f32x16 __attribute__((ext_vector_type(16)));
typedef float f32x4 __attribute__((ext_vector_type(4)));

// ============ prep: codebook norms + fragment-ready bf16 codebook ============
__global__ __launch_bounds__(256) void prep_cb(const float* __restrict__ cb,
                                               float* __restrict__ cbnorm,
                                               __bf16* __restrict__ cbf,
                                               float* __restrict__ lacc) {
  int w = threadIdx.x >> 6, lane = threadIdx.x & 63;
  int row = blockIdx.x * 4 + w;                 // 0..4095 = q*1024 + k
  int q = row >> 10, k = row & 1023;
  const f32x4* c4 = (const f32x4*)(cb + (size_t)row * Dq);
  f32x4 v0 = c4[lane * 2], v1 = c4[lane * 2 + 1];
  float s = v0.x*v0.x + v0.y*v0.y + v0.z*v0.z + v0.w*v0.w
          + v1.x*v1.x + v1.y*v1.y + v1.z*v1.z + v1.w*v1.w;
  bf16x8 bv;
  bv[0]=(__bf16)v0.x; bv[1]=(__bf16)v0.y; bv[2]=(__bf16)v0.z; bv[3]=(__bf16)v0.w;
  bv[4]=(__bf16)v1.x; bv[5]=(__bf16)v1.y; bv[6]=(__bf16)v1.z; bv[7]=(__bf16)v1.w;
  // fragment layout: [blk=k>>5][ds=lane>>1][hs=lane&1][l31=k&31][8]
  int ds = lane >> 1, hs = lane & 1;
  size_t off = ((size_t)((k >> 5) * 32 + ds) * 2 + hs) * 256 + (k & 31) * 8;
  *(bf16x8*)(cbf + (size_t)q * (Kk * Dq) + off) = bv;
#pragma unroll
  for (int off2 = 32; off2; off2 >>= 1) s += __shfl_down(s, off2);
  if (lane == 0) cbnorm[row] = s;
  if (blockIdx.x == 0 && threadIdx.x == 0) *lacc = 0.f;
}

__global__ __launch_bounds__(256) void prep_cmax(const float* __restrict__ cbnorm,
                                                 float* __restrict__ cmax) {
  int w = threadIdx.x >> 6, lane = threadIdx.x & 63;
  float m = 0.f;
#pragma unroll
  for (int j = 0; j < 16; ++j) m = fmaxf(m, cbnorm[w * Kk + lane * 16 + j]);
#pragma unroll
  for (int off = 32; off; off >>= 1) m = fmaxf(m, __shfl_down(m, off));
  if (lane == 0) cmax[w] = sqrtf(m);
}

// ============ prep: fragment-ready bf16 conv weights ============
__global__ __launch_bounds__(256) void prep_wb(const float* __restrict__ w,
                                               __bf16* __restrict__ wb) {
  int g = blockIdx.x * 256 + threadIdx.x;       // 0..163839
  int l31 = g & 31, hs = (g >> 5) & 1, c32 = (g >> 6) & 15, s = g >> 10;
  int kw = s >> 5, ci16 = s & 31;
  int ci = ci16 * 16 + hs * 8;
  int co = c32 * 32 + l31;
  bf16x8 bv;
#pragma unroll
  for (int e = 0; e < 8; ++e)
    bv[e] = (__bf16)w[(size_t)(kw * Dq + ci + e) * Dq + co];
  *(bf16x8*)(wb + (size_t)g * 8) = bv;
}

// ============ fully-fused residual VQ: 4 steps, residual in registers ========
// 512 thr = 8 waves; 64 rows/block; grid 512 (all 32768 rows, one dispatch)
__global__ __launch_bounds__(512, 1) void vq_all(
    const float* __restrict__ x, float* __restrict__ qo,
    const __bf16* __restrict__ cbf, const float* __restrict__ cb,
    const float* __restrict__ cbnorm, const float* __restrict__ cmax,
    float* __restrict__ idxo, float* __restrict__ lacc) {
  __shared__ __bf16 rh[64 * 512];               // 64KB swizzled residual
  __shared__ unsigned redB[64 * 8];
  __shared__ float rnorm_l[64];
  __shared__ float thrL[64];
  __shared__ int rowcount[64];
  __shared__ unsigned short rowlist[64 * 32];

  const int tid = threadIdx.x;
  const int w = tid >> 6, lane = tid & 63, l31 = lane & 31, hs = lane >> 5;
  const int row0g = blockIdx.x * 64;
  char* rhc = (char*)rh;

  // residual state: wave w rows w*8+rr, lane holds d = lane*8..lane*8+7
  f32x4 r0[8], r1[8];
#pragma unroll
  for (int rr = 0; rr < 8; ++rr) {
    size_t gb = (size_t)(row0g + w * 8 + rr) * Dq + lane * 8;
    r0[rr] = *(const f32x4*)(x + gb);
    r1[rr] = *(const f32x4*)(x + gb + 4);
  }
  float lsum = 0.f;

#pragma unroll 1
  for (int qi = 0; qi < Qn; ++qi) {
    const __bf16* cbf_q = cbf + (size_t)qi * (Kk * Dq);
    const float*  cb_q  = cb  + (size_t)qi * (Kk * Dq);
    const float*  cbn_q = cbnorm + qi * Kk;

    // ---- stage bf16 residual to LDS + per-row ||r||^2 ----
#pragma unroll
    for (int rr = 0; rr < 8; ++rr) {
      int row = w * 8 + rr;
      bf16x8 bv;
      bv[0]=(__bf16)r0[rr].x; bv[1]=(__bf16)r0[rr].y;
      bv[2]=(__bf16)r0[rr].z; bv[3]=(__bf16)r0[rr].w;
      bv[4]=(__bf16)r1[rr].x; bv[5]=(__bf16)r1[rr].y;
      bv[6]=(__bf16)r1[rr].z; bv[7]=(__bf16)r1[rr].w;
      *(bf16x8*)(rhc + ((row * 1024 + lane * 16) ^ ((row & 7) << 4))) = bv;
      float rn = r0[rr].x*r0[rr].x + r0[rr].y*r0[rr].y + r0[rr].z*r0[rr].z + r0[rr].w*r0[rr].w
               + r1[rr].x*r1[rr].x + r1[rr].y*r1[rr].y + r1[rr].z*r1[rr].z + r1[rr].w*r1[rr].w;
#pragma unroll
      for (int off = 1; off < 64; off <<= 1) rn += __shfl_xor(rn, off);
      if (lane == 0) rnorm_l[row] = rn;
    }
    __syncthreads();                            // A: rh ready

    // ---- MFMA screen: wave w owns cols w*128..+127; scores kept in regs ----
    unsigned ps0[16][2], ps1[16][2];
#pragma unroll
    for (int i = 0; i < 16; ++i) {
      ps0[i][0] = 0; ps0[i][1] = 0; ps1[i][0] = 0; ps1[i][1] = 0;
    }
    const int ab0 = l31 * 1024 + hs * 16;
    const int asw = (l31 & 7) << 4;
#pragma unroll 1
    for (int ct = 0; ct < 4; ++ct) {
      const int col = w * 128 + ct * 32 + l31;
      const __bf16* bp = cbf_q + (size_t)(w * 4 + ct) * 16384 + hs * 256 + l31 * 8;
      f32x16 acc0, acc1;
#pragma unroll
      for (int i = 0; i < 16; ++i) { acc0[i] = 0.f; acc1[i] = 0.f; }
#pragma unroll 8
      for (int ds = 0; ds < 32; ++ds) {
        bf16x8 b  = *(const bf16x8*)(bp + ds * 512);
        bf16x8 a0 = *(const bf16x8*)(rhc + ((ab0 + ds * 32) ^ asw));
        bf16x8 a1 = *(const bf16x8*)(rhc + ((ab0 + 32 * 1024 + ds * 32) ^ asw));
        acc0 = __builtin_amdgcn_mfma_f32_32x32x16_bf16(a0, b, acc0, 0, 0, 0);
        acc1 = __builtin_amdgcn_mfma_f32_32x32x16_bf16(a1, b, acc1, 0, 0, 0);
      }
      const float cn = cbn_q[col];
#pragma unroll
      for (int i = 0; i < 16; ++i) {
        __bf16 h0 = (__bf16)(cn - 2.f * acc0[i]);
        __bf16 h1 = (__bf16)(cn - 2.f * acc1[i]);
        ps0[i][ct >> 1] |= (unsigned)__builtin_bit_cast(unsigned short, h0) << ((ct & 1) * 16);
        ps1[i][ct >> 1] |= (unsigned)__builtin_bit_cast(unsigned short, h1) << ((ct & 1) * 16);
      }
    }

    // ---- per-row packed (score,col) argmin across this wave's 128 cols ----
    unsigned pk0[16], pk1[16];
#pragma unroll
    for (int i = 0; i < 16; ++i) {
      pk0[i] = 0xFFFFFFFFu; pk1[i] = 0xFFFFFFFFu;
#pragma unroll
      for (int ct = 0; ct < 4; ++ct) {
        unsigned col = w * 128 + ct * 32 + l31;
        unsigned u0 = (ps0[i][ct >> 1] >> ((ct & 1) * 16)) & 0xFFFFu;
        unsigned k0 = (u0 & 0x8000u) ? (u0 ^ 0xFFFFu) : (u0 | 0x8000u);
        unsigned p0 = (k0 << 10) | col;
        if (p0 < pk0[i]) pk0[i] = p0;
        unsigned u1 = (ps1[i][ct >> 1] >> ((ct & 1) * 16)) & 0xFFFFu;
        unsigned k1 = (u1 & 0x8000u) ? (u1 ^ 0xFFFFu) : (u1 | 0x8000u);
        unsigned p1 = (k1 << 10) | col;
        if (p1 < pk1[i]) pk1[i] = p1;
      }
#pragma unroll
      for (int off = 1; off <= 16; off <<= 1) {
        unsigned t0 = __shfl_xor(pk0[i], off);
        if (t0 < pk0[i]) pk0[i] = t0;
        unsigned t1 = __shfl_xor(pk1[i], off);
        if (t1 < pk1[i]) pk1[i] = t1;
      }
    }
    if (l31 == 0) {
#pragma unroll
      for (int i = 0; i < 16; ++i) {
        int rit = (i & 3) + 8 * (i >> 2) + 4 * hs;
        redB[rit * 8 + w] = pk0[i];
        redB[(32 + rit) * 8 + w] = pk1[i];
      }
    }
    __syncthreads();                            // B: redB ready

    if (tid < 64) {
      unsigned mb = redB[tid * 8];
#pragma unroll
      for (int j = 1; j < 8; ++j) {
        unsigned v = redB[tid * 8 + j];
        if (v < mb) mb = v;
      }
      unsigned key = (mb >> 10) & 0xFFFFu;
      unsigned ub = (key & 0x8000u) ? (key ^ 0x8000u) : (key ^ 0xFFFFu);
      float mstar = __uint_as_float(ub << 16);
      float rn = sqrtf(rnorm_l[tid]);
      float cm = cmax[qi];
      thrL[tid] = mstar + 0.025f * rn * cm + 0.0045f * cm * cm;
      rowcount[tid] = 0;
    }
    __syncthreads();                            // C: thr ready

    // ---- candidate scan from register scores ----
#pragma unroll
    for (int i = 0; i < 16; ++i) {
      int rit = (i & 3) + 8 * (i >> 2) + 4 * hs;
      float t0 = thrL[rit], t1 = thrL[32 + rit];
#pragma unroll
      for (int ct = 0; ct < 4; ++ct) {
        unsigned col = w * 128 + ct * 32 + l31;
        unsigned u0 = (ps0[i][ct >> 1] >> ((ct & 1) * 16)) & 0xFFFFu;
        float s0 = __uint_as_float(u0 << 16);
        if (s0 <= t0) {
          int p = atomicAdd(&rowcount[rit], 1);
          if (p < 32) rowlist[rit * 32 + p] = (unsigned short)col;
        }
        unsigned u1 = (ps1[i][ct >> 1] >> ((ct & 1) * 16)) & 0xFFFFu;
        float s1 = __uint_as_float(u1 << 16);
        if (s1 <= t1) {
          int p = atomicAdd(&rowcount[32 + rit], 1);
          if (p < 32) rowlist[(32 + rit) * 32 + p] = (unsigned short)col;
        }
      }
    }
    __syncthreads();                            // D: rowlist ready

    // ---- exact f32 rescore + register residual update ----
#pragma unroll
    for (int rr = 0; rr < 8; ++rr) {
      int row = w * 8 + rr;
      int cnt = rowcount[row];
      int total = (cnt > 32) ? Kk : cnt;
      float bs = 3.4028235e38f; int bk = 1 << 30;
      for (int ci2 = 0; ci2 < total; ++ci2) {
        int k = (cnt > 32) ? ci2 : (int)rowlist[row * 32 + ci2];
        const f32x4* crow = (const f32x4*)(cb_q + ((size_t)k << 9)) + lane * 2;
        f32x4 c0 = crow[0], c1 = crow[1];
        float dot = 0.f;
        dot = fmaf(r0[rr].x, c0.x, dot); dot = fmaf(r0[rr].y, c0.y, dot);
        dot = fmaf(r0[rr].z, c0.z, dot); dot = fmaf(r0[rr].w, c0.w, dot);
        dot = fmaf(r1[rr].x, c1.x, dot); dot = fmaf(r1[rr].y, c1.y, dot);
        dot = fmaf(r1[rr].z, c1.z, dot); dot = fmaf(r1[rr].w, c1.w, dot);
#pragma unroll
        for (int off = 1; off < 64; off <<= 1) dot += __shfl_xor(dot, off);
        float sc = cbn_q[k] - 2.f * dot;
        if (sc < bs || (sc == bs && k < bk)) { bs = sc; bk = k; }
      }
      if (lane == 0) idxo[(size_t)qi * NROWS + row0g + row] = (float)bk;
      const f32x4* crow = (const f32x4*)(cb_q + ((size_t)bk << 9)) + lane * 2;
      f32x4 c0 = crow[0], c1 = crow[1];
      r0[rr].x -= c0.x; r0[rr].y -= c0.y; r0[rr].z -= c0.z; r0[rr].w -= c0.w;
      r1[rr].x -= c1.x; r1[rr].y -= c1.y; r1[rr].z -= c1.z; r1[rr].w -= c1.w;
      lsum += r0[rr].x*r0[rr].x + r0[rr].y*r0[rr].y + r0[rr].z*r0[rr].z + r0[rr].w*r0[rr].w
            + r1[rr].x*r1[rr].x + r1[rr].y*r1[rr].y + r1[rr].z*r1[rr].z + r1[rr].w*r1[rr].w;
    }
    __syncthreads();                            // E: done with rh/lists this step
  }

  // ---- write quantized_out = x - r_final ----
#pragma unroll
  for (int rr = 0; rr < 8; ++rr) {
    size_t gb = (size_t)(row0g + w * 8 + rr) * Dq + lane * 8;
    f32x4 xv0 = *(const f32x4*)(x + gb), xv1 = *(const f32x4*)(x + gb + 4);
    f32x4 o0, o1;
    o0.x = xv0.x - r0[rr].x; o0.y = xv0.y - r0[rr].y;
    o0.z = xv0.z - r0[rr].z; o0.w = xv0.w - r0[rr].w;
    o1.x = xv1.x - r1[rr].x; o1.y = xv1.y - r1[rr].y;
    o1.z = xv1.z - r1[rr].z; o1.w = xv1.w - r1[rr].w;
    *(f32x4*)(qo + gb) = o0;
    *(f32x4*)(qo + gb + 4) = o1;
  }
#pragma unroll
  for (int off = 1; off < 64; off <<= 1) lsum += __shfl_xor(lsum, off);
  if (lane == 0) atomicAdd(lacc, lsum);
}

// ============ conv1d stride2 SAME via bf16 MFMA + exact GELU ============
__global__ __launch_bounds__(512, 2) void conv_mfma(const float* __restrict__ qo,
                                                    const __bf16* __restrict__ wb,
                                                    float* __restrict__ y) {
  __shared__ char As[259 * 128];                // 259 input rows x 64 ci bf16
  const int tid = threadIdx.x;
  const int w = tid >> 6, lane = tid & 63, l31 = lane & 31, hs = lane >> 5;
  const int rowblk = blockIdx.x, coblk = blockIdx.y;
  const int n = rowblk >> 4;
  const int o0 = (rowblk & 15) * 128;
  const int t0 = 2 * o0 - 1;
  const int c32g = coblk * 8 + w;

  f32x16 acc[4];
#pragma unroll
  for (int rt = 0; rt < 4; ++rt)
#pragma unroll
    for (int i = 0; i < 16; ++i) acc[rt][i] = 0.f;

  for (int ct8 = 0; ct8 < 8; ++ct8) {
    __syncthreads();
    for (int s = tid; s < 2072; s += 512) {
      int irow = s >> 3, cg = s & 7;
      int t = t0 + irow;
      bf16x8 bv;
      if (t >= 0 && t < Tq) {
        const float* src = qo + ((size_t)(n * Tq + t)) * Dq + ct8 * 64 + cg * 8;
        f32x4 v0 = *(const f32x4*)(src), v1 = *(const f32x4*)(src + 4);
        bv[0]=(__bf16)v0.x; bv[1]=(__bf16)v0.y; bv[2]=(__bf16)v0.z; bv[3]=(__bf16)v0.w;
        bv[4]=(__bf16)v1.x; bv[5]=(__bf16)v1.y; bv[6]=(__bf16)v1.z; bv[7]=(__bf16)v1.w;
      } else {
#pragma unroll
        for (int e = 0; e < 8; ++e) bv[e] = (__bf16)0.f;
      }
      *(bf16x8*)(As + ((irow * 128 + cg * 16) ^ (((irow >> 1) & 7) << 4))) = bv;
    }
    __syncthreads();
#pragma unroll
    for (int kw = 0; kw < 5; ++kw) {
#pragma unroll
      for (int ks = 0; ks < 4; ++ks) {
        int s16 = kw * 32 + ct8 * 4 + ks;
        bf16x8 b = *(const bf16x8*)(wb + ((size_t)(s16 * 16 + c32g) * 2 + hs) * 256 + l31 * 8);
#pragma unroll
        for (int rt = 0; rt < 4; ++rt) {
          int ir = 2 * (rt * 32 + l31) + kw;
          bf16x8 a = *(const bf16x8*)(As + ((ir * 128 + ks * 32 + hs * 16) ^ (((ir >> 1) & 7) << 4)));
          acc[rt] = __builtin_amdgcn_mfma_f32_32x32x16_bf16(a, b, acc[rt], 0, 0, 0);
        }
      }
    }
  }
  const int co = coblk * 256 + w * 32 + l31;
#pragma unroll
  for (int rt = 0; rt < 4; ++rt)
#pragma unroll
    for (int i = 0; i < 16; ++i) {
      int orow = rt * 32 + (i & 3) + 8 * (i >> 2) + 4 * hs;
      float v = acc[rt][i];
      float g = 0.5f * v * (1.f + erff(v * 0.70710678118654752f));
      y[((size_t)(n * OWn + o0 + orow)) * Dq + co] = g;
    }
}

__global__ void loss_final(const float* __restrict__ lacc, float* __restrict__ out) {
  out[0] = 0.25f * lacc[0] / 16777216.0f;
}

extern "C" void kernel_launch(void* const* d_in, const int* in_sizes, int n_in,
                              void* d_out, int out_size, void* d_ws, size_t ws_size,
                              hipStream_t stream) {
  const float* x  = (const float*)d_in[0];
  const float* cb = (const float*)d_in[1];
  const float* cw = (const float*)d_in[2];
  float* out = (float*)d_out;
  float* y    = out;
  float* qo   = out + QO_OFF;
  float* idxo = out + IDX_OFF;
  float* losso = out + LOSS_OFF;

  float* fws    = (float*)d_ws;
  float* lacc   = fws;                // 1
  float* cmax   = fws + 8;            // 4
  float* cbnorm = fws + 16;           // 4096
  __bf16* cbf = (__bf16*)((char*)d_ws + (32 << 10));        // 4 MB
  __bf16* wb  = (__bf16*)((char*)d_ws + (8 << 20));         // 2.62 MB

  prep_cb<<<1024, 256, 0, stream>>>(cb, cbnorm, cbf, lacc);
  prep_cmax<<<1, 256, 0, stream>>>(cbnorm, cmax);
  prep_wb<<<640, 256, 0, stream>>>(cw, wb);

  vq_all<<<512, 512, 0, stream>>>(x, qo, cbf, cb, cbnorm, cmax, idxo, lacc);

  conv_mfma<<<dim3(128, 2), 512, 0, stream>>>(qo, wb, y);
  loss_final<<<1, 1, 0, stream>>>(lacc, losso);
}

// Round 5
// 581.026 us; speedup vs baseline: 5.2200x; 1.1103x over previous
//
#include <hip/hip_runtime.h>
#include <math.h>

#define Bq 8
#define Tq 4096
#define Dq 512
#define Qn 4
#define Kk 1024
#define OWn 2048
#define NROWS (Bq*Tq)

#define QO_OFF (Bq*OWn*Dq)
#define IDX_OFF (QO_OFF + Bq*Tq*Dq)
#define LOSS_OFF (IDX_OFF + Qn*NROWS)

typedef __bf16 bf16x8 __attribute__((ext_vector_type(8)));
typedef float f32x16 __attribute__((ext_vector_type(16)));
typedef float f32x4 __attribute__((ext_vector_type(4)));

// ============ prep: codebook norms + fragment-ready bf16 codebook ============
__global__ __launch_bounds__(256) void prep_cb(const float* __restrict__ cb,
                                               float* __restrict__ cbnorm,
                                               __bf16* __restrict__ cbf,
                                               float* __restrict__ lacc) {
  int w = threadIdx.x >> 6, lane = threadIdx.x & 63;
  int row = blockIdx.x * 4 + w;                 // 0..4095 = q*1024 + k
  int q = row >> 10, k = row & 1023;
  const f32x4* c4 = (const f32x4*)(cb + (size_t)row * Dq);
  f32x4 v0 = c4[lane * 2], v1 = c4[lane * 2 + 1];
  float s = v0.x*v0.x + v0.y*v0.y + v0.z*v0.z + v0.w*v0.w
          + v1.x*v1.x + v1.y*v1.y + v1.z*v1.z + v1.w*v1.w;
  bf16x8 bv;
  bv[0]=(__bf16)v0.x; bv[1]=(__bf16)v0.y; bv[2]=(__bf16)v0.z; bv[3]=(__bf16)v0.w;
  bv[4]=(__bf16)v1.x; bv[5]=(__bf16)v1.y; bv[6]=(__bf16)v1.z; bv[7]=(__bf16)v1.w;
  // fragment layout: [blk=k>>5][ds=lane>>1][hs=lane&1][l31=k&31][8]
  int ds = lane >> 1, hs = lane & 1;
  size_t off = ((size_t)((k >> 5) * 32 + ds) * 2 + hs) * 256 + (k & 31) * 8;
  *(bf16x8*)(cbf + (size_t)q * (Kk * Dq) + off) = bv;
#pragma unroll
  for (int off2 = 32; off2; off2 >>= 1) s += __shfl_down(s, off2);
  if (lane == 0) cbnorm[row] = s;
  if (blockIdx.x == 0 && threadIdx.x == 0) *lacc = 0.f;
}

__global__ __launch_bounds__(256) void prep_cmax(const float* __restrict__ cbnorm,
                                                 float* __restrict__ cmax) {
  int w = threadIdx.x >> 6, lane = threadIdx.x & 63;
  float m = 0.f;
#pragma unroll
  for (int j = 0; j < 16; ++j) m = fmaxf(m, cbnorm[w * Kk + lane * 16 + j]);
#pragma unroll
  for (int off = 32; off; off >>= 1) m = fmaxf(m, __shfl_down(m, off));
  if (lane == 0) cmax[w] = sqrtf(m);
}

// ============ prep: fragment-ready bf16 conv weights ============
__global__ __launch_bounds__(256) void prep_wb(const float* __restrict__ w,
                                               __bf16* __restrict__ wb) {
  int g = blockIdx.x * 256 + threadIdx.x;       // 0..163839
  int l31 = g & 31, hs = (g >> 5) & 1, c32 = (g >> 6) & 15, s = g >> 10;
  int kw = s >> 5, ci16 = s & 31;
  int ci = ci16 * 16 + hs * 8;
  int co = c32 * 32 + l31;
  bf16x8 bv;
#pragma unroll
  for (int e = 0; e < 8; ++e)
    bv[e] = (__bf16)w[(size_t)(kw * Dq + ci + e) * Dq + co];
  *(bf16x8*)(wb + (size_t)g * 8) = bv;
}

// ============ fully-fused residual VQ: 4 steps, residual in registers ========
// 512 thr = 8 waves; 32 rows/block; wave w: residual rows w*4..w*4+3,
// screen cols w*128..w*128+127. grid 1024 (all rows, one dispatch).
__global__ __launch_bounds__(512, 2) void vq_all(
    const float* __restrict__ x, float* __restrict__ qo,
    const __bf16* __restrict__ cbf, const float* __restrict__ cb,
    const float* __restrict__ cbnorm, const float* __restrict__ cmax,
    float* __restrict__ idxo, float* __restrict__ lacc) {
  __shared__ __bf16 rh[32 * 512];               // 32KB swizzled residual tile
  __shared__ unsigned redB[32 * 8];
  __shared__ float rnorm_l[32];
  __shared__ float thrL[32];
  __shared__ int rowcount[32];
  __shared__ unsigned short rowlist[32 * 32];

  const int tid = threadIdx.x;
  const int w = tid >> 6, lane = tid & 63, l31 = lane & 31, hs = lane >> 5;
  const int row0g = blockIdx.x * 32;
  char* rhc = (char*)rh;

  // residual state: wave w rows w*4+rr, lane holds d = lane*8..lane*8+7
  f32x4 r0[4], r1[4];
#pragma unroll
  for (int rr = 0; rr < 4; ++rr) {
    size_t gb = (size_t)(row0g + w * 4 + rr) * Dq + lane * 8;
    r0[rr] = *(const f32x4*)(x + gb);
    r1[rr] = *(const f32x4*)(x + gb + 4);
  }
  float lsum = 0.f;

#pragma unroll 1
  for (int qi = 0; qi < Qn; ++qi) {
    const __bf16* cbf_q = cbf + (size_t)qi * (Kk * Dq);
    const float*  cb_q  = cb  + (size_t)qi * (Kk * Dq);
    const float*  cbn_q = cbnorm + qi * Kk;

    // ---- stage bf16 residual to LDS + per-row ||r||^2 ----
#pragma unroll
    for (int rr = 0; rr < 4; ++rr) {
      int row = w * 4 + rr;
      bf16x8 bv;
      bv[0]=(__bf16)r0[rr].x; bv[1]=(__bf16)r0[rr].y;
      bv[2]=(__bf16)r0[rr].z; bv[3]=(__bf16)r0[rr].w;
      bv[4]=(__bf16)r1[rr].x; bv[5]=(__bf16)r1[rr].y;
      bv[6]=(__bf16)r1[rr].z; bv[7]=(__bf16)r1[rr].w;
      *(bf16x8*)(rhc + ((row * 1024 + lane * 16) ^ ((row & 7) << 4))) = bv;
      float rn = r0[rr].x*r0[rr].x + r0[rr].y*r0[rr].y + r0[rr].z*r0[rr].z + r0[rr].w*r0[rr].w
               + r1[rr].x*r1[rr].x + r1[rr].y*r1[rr].y + r1[rr].z*r1[rr].z + r1[rr].w*r1[rr].w;
#pragma unroll
      for (int off = 1; off < 64; off <<= 1) rn += __shfl_xor(rn, off);
      if (lane == 0) rnorm_l[row] = rn;
    }
    __syncthreads();                            // A: rh ready

    // ---- MFMA screen: wave w owns cols w*128..+127 (4 ct of 32), 2 ct-pairs,
    //      ds outer so each A-fragment feeds 2 MFMAs; scores packed in regs ---
    unsigned ps[4][8];                          // [ct][j]: scores 2j,2j+1 (all static idx)
    const int ab0 = l31 * 1024 + hs * 16;
    const int asw = (l31 & 7) << 4;
#pragma unroll
    for (int p = 0; p < 2; ++p) {
      const int ctA = 2 * p, ctB = 2 * p + 1;
      const __bf16* bpA = cbf_q + (size_t)(w * 4 + ctA) * 16384 + hs * 256 + l31 * 8;
      const __bf16* bpB = cbf_q + (size_t)(w * 4 + ctB) * 16384 + hs * 256 + l31 * 8;
      f32x16 accA, accB;
#pragma unroll
      for (int i = 0; i < 16; ++i) { accA[i] = 0.f; accB[i] = 0.f; }
#pragma unroll 8
      for (int ds = 0; ds < 32; ++ds) {
        bf16x8 a  = *(const bf16x8*)(rhc + ((ab0 + ds * 32) ^ asw));
        bf16x8 b0 = *(const bf16x8*)(bpA + ds * 512);
        bf16x8 b1 = *(const bf16x8*)(bpB + ds * 512);
        accA = __builtin_amdgcn_mfma_f32_32x32x16_bf16(a, b0, accA, 0, 0, 0);
        accB = __builtin_amdgcn_mfma_f32_32x32x16_bf16(a, b1, accB, 0, 0, 0);
      }
      const float cnA = cbn_q[w * 128 + ctA * 32 + l31];
      const float cnB = cbn_q[w * 128 + ctB * 32 + l31];
#pragma unroll
      for (int j = 0; j < 8; ++j) {
        __bf16 hA0 = (__bf16)(cnA - 2.f * accA[2 * j]);
        __bf16 hA1 = (__bf16)(cnA - 2.f * accA[2 * j + 1]);
        __bf16 hB0 = (__bf16)(cnB - 2.f * accB[2 * j]);
        __bf16 hB1 = (__bf16)(cnB - 2.f * accB[2 * j + 1]);
        ps[ctA][j] = (unsigned)__builtin_bit_cast(unsigned short, hA0)
                   | ((unsigned)__builtin_bit_cast(unsigned short, hA1) << 16);
        ps[ctB][j] = (unsigned)__builtin_bit_cast(unsigned short, hB0)
                   | ((unsigned)__builtin_bit_cast(unsigned short, hB1) << 16);
      }
    }

    // ---- per-row packed (score,col) argmin across this wave's 128 cols ----
    unsigned pk[16];
#pragma unroll
    for (int i = 0; i < 16; ++i) {
      pk[i] = 0xFFFFFFFFu;
#pragma unroll
      for (int ct = 0; ct < 4; ++ct) {
        unsigned col = (unsigned)(w * 128 + ct * 32 + l31);
        unsigned u = (ps[ct][i >> 1] >> ((i & 1) * 16)) & 0xFFFFu;
        unsigned key = (u & 0x8000u) ? (u ^ 0xFFFFu) : (u | 0x8000u);
        unsigned pkc = (key << 10) | col;
        if (pkc < pk[i]) pk[i] = pkc;
      }
#pragma unroll
      for (int off = 1; off <= 16; off <<= 1) {
        unsigned t = __shfl_xor(pk[i], off);
        if (t < pk[i]) pk[i] = t;
      }
    }
    if (l31 == 0) {
#pragma unroll
      for (int i = 0; i < 16; ++i) {
        int rit = (i & 3) + 8 * (i >> 2) + 4 * hs;
        redB[rit * 8 + w] = pk[i];
      }
    }
    __syncthreads();                            // B: redB ready

    if (tid < 32) {
      unsigned mb = redB[tid * 8];
#pragma unroll
      for (int j = 1; j < 8; ++j) {
        unsigned v = redB[tid * 8 + j];
        if (v < mb) mb = v;
      }
      unsigned key = (mb >> 10) & 0xFFFFu;
      unsigned ub = (key & 0x8000u) ? (key ^ 0x8000u) : (key ^ 0xFFFFu);
      float mstar = __uint_as_float(ub << 16);
      float rn = sqrtf(rnorm_l[tid]);
      float cm = cmax[qi];
      thrL[tid] = mstar + 0.025f * rn * cm + 0.0045f * cm * cm;
      rowcount[tid] = 0;
    }
    __syncthreads();                            // C: thr ready

    // ---- candidate scan from register scores ----
#pragma unroll
    for (int i = 0; i < 16; ++i) {
      int rit = (i & 3) + 8 * (i >> 2) + 4 * hs;
      float t = thrL[rit];
#pragma unroll
      for (int ct = 0; ct < 4; ++ct) {
        unsigned col = (unsigned)(w * 128 + ct * 32 + l31);
        unsigned u = (ps[ct][i >> 1] >> ((i & 1) * 16)) & 0xFFFFu;
        float s = __uint_as_float(u << 16);
        if (s <= t) {
          int p = atomicAdd(&rowcount[rit], 1);
          if (p < 32) rowlist[rit * 32 + p] = (unsigned short)col;
        }
      }
    }
    __syncthreads();                            // D: rowlist ready

    // ---- exact f32 rescore + register residual update ----
#pragma unroll
    for (int rr = 0; rr < 4; ++rr) {
      int row = w * 4 + rr;
      int cnt = rowcount[row];
      int total = (cnt > 32) ? Kk : cnt;
      float bs = 3.4028235e38f; int bk = 1 << 30;
      for (int ci2 = 0; ci2 < total; ++ci2) {
        int k = (cnt > 32) ? ci2 : (int)rowlist[row * 32 + ci2];
        const f32x4* crow = (const f32x4*)(cb_q + ((size_t)k << 9)) + lane * 2;
        f32x4 c0 = crow[0], c1 = crow[1];
        float dot = 0.f;
        dot = fmaf(r0[rr].x, c0.x, dot); dot = fmaf(r0[rr].y, c0.y, dot);
        dot = fmaf(r0[rr].z, c0.z, dot); dot = fmaf(r0[rr].w, c0.w, dot);
        dot = fmaf(r1[rr].x, c1.x, dot); dot = fmaf(r1[rr].y, c1.y, dot);
        dot = fmaf(r1[rr].z, c1.z, dot); dot = fmaf(r1[rr].w, c1.w, dot);
#pragma unroll
        for (int off = 1; off < 64; off <<= 1) dot += __shfl_xor(dot, off);
        float sc = cbn_q[k] - 2.f * dot;
        if (sc < bs || (sc == bs && k < bk)) { bs = sc; bk = k; }
      }
      if (lane == 0) idxo[(size_t)qi * NROWS + row0g + row] = (float)bk;
      const f32x4* crow = (const f32x4*)(cb_q + ((size_t)bk << 9)) + lane * 2;
      f32x4 c0 = crow[0], c1 = crow[1];
      r0[rr].x -= c0.x; r0[rr].y -= c0.y; r0[rr].z -= c0.z; r0[rr].w -= c0.w;
      r1[rr].x -= c1.x; r1[rr].y -= c1.y; r1[rr].z -= c1.z; r1[rr].w -= c1.w;
      lsum += r0[rr].x*r0[rr].x + r0[rr].y*r0[rr].y + r0[rr].z*r0[rr].z + r0[rr].w*r0[rr].w
            + r1[rr].x*r1[rr].x + r1[rr].y*r1[rr].y + r1[rr].z*r1[rr].z + r1[rr].w*r1[rr].w;
    }
    __syncthreads();                            // E: step done
  }

  // ---- write quantized_out = x - r_final ----
#pragma unroll
  for (int rr = 0; rr < 4; ++rr) {
    size_t gb = (size_t)(row0g + w * 4 + rr) * Dq + lane * 8;
    f32x4 xv0 = *(const f32x4*)(x + gb), xv1 = *(const f32x4*)(x + gb + 4);
    f32x4 o0, o1;
    o0.x = xv0.x - r0[rr].x; o0.y = xv0.y - r0[rr].y;
    o0.z = xv0.z - r0[rr].z; o0.w = xv0.w - r0[rr].w;
    o1.x = xv1.x - r1[rr].x; o1.y = xv1.y - r1[rr].y;
    o1.z = xv1.z - r1[rr].z; o1.w = xv1.w - r1[rr].w;
    *(f32x4*)(qo + gb) = o0;
    *(f32x4*)(qo + gb + 4) = o1;
  }
#pragma unroll
  for (int off = 1; off < 64; off <<= 1) lsum += __shfl_xor(lsum, off);
  if (lane == 0) atomicAdd(lacc, lsum);
}

// ============ conv1d stride2 SAME via bf16 MFMA + exact GELU ============
__global__ __launch_bounds__(512, 2) void conv_mfma(const float* __restrict__ qo,
                                                    const __bf16* __restrict__ wb,
                                                    float* __restrict__ y) {
  __shared__ char As[259 * 128];                // 259 input rows x 64 ci bf16
  const int tid = threadIdx.x;
  const int w = tid >> 6, lane = tid & 63, l31 = lane & 31, hs = lane >> 5;
  const int rowblk = blockIdx.x, coblk = blockIdx.y;
  const int n = rowblk >> 4;
  const int o0 = (rowblk & 15) * 128;
  const int t0 = 2 * o0 - 1;
  const int c32g = coblk * 8 + w;

  f32x16 acc[4];
#pragma unroll
  for (int rt = 0; rt < 4; ++rt)
#pragma unroll
    for (int i = 0; i < 16; ++i) acc[rt][i] = 0.f;

  for (int ct8 = 0; ct8 < 8; ++ct8) {
    __syncthreads();
    for (int s = tid; s < 2072; s += 512) {
      int irow = s >> 3, cg = s & 7;
      int t = t0 + irow;
      bf16x8 bv;
      if (t >= 0 && t < Tq) {
        const float* src = qo + ((size_t)(n * Tq + t)) * Dq + ct8 * 64 + cg * 8;
        f32x4 v0 = *(const f32x4*)(src), v1 = *(const f32x4*)(src + 4);
        bv[0]=(__bf16)v0.x; bv[1]=(__bf16)v0.y; bv[2]=(__bf16)v0.z; bv[3]=(__bf16)v0.w;
        bv[4]=(__bf16)v1.x; bv[5]=(__bf16)v1.y; bv[6]=(__bf16)v1.z; bv[7]=(__bf16)v1.w;
      } else {
#pragma unroll
        for (int e = 0; e < 8; ++e) bv[e] = (__bf16)0.f;
      }
      *(bf16x8*)(As + ((irow * 128 + cg * 16) ^ (((irow >> 1) & 7) << 4))) = bv;
    }
    __syncthreads();
#pragma unroll
    for (int kw = 0; kw < 5; ++kw) {
#pragma unroll
      for (int ks = 0; ks < 4; ++ks) {
        int s16 = kw * 32 + ct8 * 4 + ks;
        bf16x8 b = *(const bf16x8*)(wb + ((size_t)(s16 * 16 + c32g) * 2 + hs) * 256 + l31 * 8);
#pragma unroll
        for (int rt = 0; rt < 4; ++rt) {
          int ir = 2 * (rt * 32 + l31) + kw;
          bf16x8 a = *(const bf16x8*)(As + ((ir * 128 + ks * 32 + hs * 16) ^ (((ir >> 1) & 7) << 4)));
          acc[rt] = __builtin_amdgcn_mfma_f32_32x32x16_bf16(a, b, acc[rt], 0, 0, 0);
        }
      }
    }
  }
  const int co = coblk * 256 + w * 32 + l31;
#pragma unroll
  for (int rt = 0; rt < 4; ++rt)
#pragma unroll
    for (int i = 0; i < 16; ++i) {
      int orow = rt * 32 + (i & 3) + 8 * (i >> 2) + 4 * hs;
      float v = acc[rt][i];
      float g = 0.5f * v * (1.f + erff(v * 0.70710678118654752f));
      y[((size_t)(n * OWn + o0 + orow)) * Dq + co] = g;
    }
}

__global__ void loss_final(const float* __restrict__ lacc, float* __restrict__ out) {
  out[0] = 0.25f * lacc[0] / 16777216.0f;
}

extern "C" void kernel_launch(void* const* d_in, const int* in_sizes, int n_in,
                              void* d_out, int out_size, void* d_ws, size_t ws_size,
                              hipStream_t stream) {
  const float* x  = (const float*)d_in[0];
  const float* cb = (const float*)d_in[1];
  const float* cw = (const float*)d_in[2];
  float* out = (float*)d_out;
  float* y    = out;
  float* qo   = out + QO_OFF;
  float* idxo = out + IDX_OFF;
  float* losso = out + LOSS_OFF;

  float* fws    = (float*)d_ws;
  float* lacc   = fws;                // 1
  float* cmax   = fws + 8;            // 4
  float* cbnorm = fws + 16;           // 4096
  __bf16* cbf = (__bf16*)((char*)d_ws + (32 << 10));        // 4 MB
  __bf16* wb  = (__bf16*)((char*)d_ws + (8 << 20));         // 2.62 MB

  prep_cb<<<1024, 256, 0, stream>>>(cb, cbnorm, cbf, lacc);
  prep_cmax<<<1, 256, 0, stream>>>(cbnorm, cmax);
  prep_wb<<<640, 256, 0, stream>>>(cw, wb);

  vq_all<<<1024, 512, 0, stream>>>(x, qo, cbf, cb, cbnorm, cmax, idxo, lacc);

  conv_mfma<<<dim3(128, 2), 512, 0, stream>>>(qo, wb, y);
  loss_final<<<1, 1, 0, stream>>>(lacc, losso);
}

// Round 6
// 502.345 us; speedup vs baseline: 6.0376x; 1.1566x over previous
//
#include <hip/hip_runtime.h>
#include <math.h>

#define Bq 8
#define Tq 4096
#define Dq 512
#define Qn 4
#define Kk 1024
#define OWn 2048
#define NROWS (Bq*Tq)

#define QO_OFF (Bq*OWn*Dq)
#define IDX_OFF (QO_OFF + Bq*Tq*Dq)
#define LOSS_OFF (IDX_OFF + Qn*NROWS)

typedef __bf16 bf16x8 __attribute__((ext_vector_type(8)));
typedef _Float16 f16x8 __attribute__((ext_vector_type(8)));
typedef float f32x16 __attribute__((ext_vector_type(16)));
typedef float f32x4 __attribute__((ext_vector_type(4)));

__device__ __forceinline__ unsigned pack2h(_Float16 a, _Float16 b) {
  return (unsigned)__builtin_bit_cast(unsigned short, a)
       | ((unsigned)__builtin_bit_cast(unsigned short, b) << 16);
}

// ============ prep: codebook norms + fragment-ready fp16 codebook ============
__global__ __launch_bounds__(256) void prep_cb(const float* __restrict__ cb,
                                               float* __restrict__ cbnorm,
                                               _Float16* __restrict__ cbf,
                                               float* __restrict__ lacc) {
  int w = threadIdx.x >> 6, lane = threadIdx.x & 63;
  int row = blockIdx.x * 4 + w;                 // 0..4095 = q*1024 + k
  int q = row >> 10, k = row & 1023;
  const f32x4* c4 = (const f32x4*)(cb + (size_t)row * Dq);
  f32x4 v0 = c4[lane * 2], v1 = c4[lane * 2 + 1];
  float s = v0.x*v0.x + v0.y*v0.y + v0.z*v0.z + v0.w*v0.w
          + v1.x*v1.x + v1.y*v1.y + v1.z*v1.z + v1.w*v1.w;
  f16x8 bv;
  bv[0]=(_Float16)v0.x; bv[1]=(_Float16)v0.y; bv[2]=(_Float16)v0.z; bv[3]=(_Float16)v0.w;
  bv[4]=(_Float16)v1.x; bv[5]=(_Float16)v1.y; bv[6]=(_Float16)v1.z; bv[7]=(_Float16)v1.w;
  // fragment layout: [blk=k>>5][ds=lane>>1][hs=lane&1][l31=k&31][8]
  int ds = lane >> 1, hs = lane & 1;
  size_t off = ((size_t)((k >> 5) * 32 + ds) * 2 + hs) * 256 + (k & 31) * 8;
  *(f16x8*)(cbf + (size_t)q * (Kk * Dq) + off) = bv;
#pragma unroll
  for (int off2 = 32; off2; off2 >>= 1) s += __shfl_down(s, off2);
  if (lane == 0) cbnorm[row] = s;
  if (blockIdx.x == 0 && threadIdx.x == 0) *lacc = 0.f;
}

__global__ __launch_bounds__(256) void prep_cmax(const float* __restrict__ cbnorm,
                                                 float* __restrict__ cmax) {
  int w = threadIdx.x >> 6, lane = threadIdx.x & 63;
  float m = 0.f;
#pragma unroll
  for (int j = 0; j < 16; ++j) m = fmaxf(m, cbnorm[w * Kk + lane * 16 + j]);
#pragma unroll
  for (int off = 32; off; off >>= 1) m = fmaxf(m, __shfl_down(m, off));
  if (lane == 0) cmax[w] = sqrtf(m);
}

// ============ prep: fragment-ready bf16 conv weights ============
__global__ __launch_bounds__(256) void prep_wb(const float* __restrict__ w,
                                               __bf16* __restrict__ wb) {
  int g = blockIdx.x * 256 + threadIdx.x;       // 0..163839
  int l31 = g & 31, hs = (g >> 5) & 1, c32 = (g >> 6) & 15, s = g >> 10;
  int kw = s >> 5, ci16 = s & 31;
  int ci = ci16 * 16 + hs * 8;
  int co = c32 * 32 + l31;
  bf16x8 bv;
#pragma unroll
  for (int e = 0; e < 8; ++e)
    bv[e] = (__bf16)w[(size_t)(kw * Dq + ci + e) * Dq + co];
  *(bf16x8*)(wb + (size_t)g * 8) = bv;
}

// ============ fully-fused residual VQ: 4 steps, residual in registers ========
// 512 thr = 8 waves; 64 rows/block (wave w: residual rows w*8..w*8+7,
// screen cols w*128..+127 x all 64 rows). grid 512.
__global__ __launch_bounds__(512, 2) void vq_all(
    const float* __restrict__ x, float* __restrict__ qo,
    const _Float16* __restrict__ cbf, const float* __restrict__ cb,
    const float* __restrict__ cbnorm, const float* __restrict__ cmax,
    float* __restrict__ idxo, float* __restrict__ lacc) {
  __shared__ _Float16 rh[64 * 512];             // 64KB swizzled residual tile
  __shared__ unsigned redB[64 * 8];
  __shared__ float rnorm_l[64];
  __shared__ float thrL[64];
  __shared__ int rowcount[64];
  __shared__ unsigned short rowlist[64 * 32];

  const int tid = threadIdx.x;
  const int w = tid >> 6, lane = tid & 63, l31 = lane & 31, hs = lane >> 5;
  const int row0g = blockIdx.x * 64;
  char* rhc = (char*)rh;

  // residual state: wave w rows w*8+rr, lane holds d = lane*8..lane*8+7
  f32x4 r0[8], r1[8];
#pragma unroll
  for (int rr = 0; rr < 8; ++rr) {
    size_t gb = (size_t)(row0g + w * 8 + rr) * Dq + lane * 8;
    r0[rr] = *(const f32x4*)(x + gb);
    r1[rr] = *(const f32x4*)(x + gb + 4);
  }
  float lsum = 0.f;

#pragma unroll 1
  for (int qi = 0; qi < Qn; ++qi) {
    const _Float16* cbf_q = cbf + (size_t)qi * (Kk * Dq);
    const float*    cb_q  = cb  + (size_t)qi * (Kk * Dq);
    const float*    cbn_q = cbnorm + qi * Kk;

    // ---- stage fp16 residual to LDS + per-row ||r||^2 ----
#pragma unroll
    for (int rr = 0; rr < 8; ++rr) {
      int row = w * 8 + rr;
      f16x8 bv;
      bv[0]=(_Float16)r0[rr].x; bv[1]=(_Float16)r0[rr].y;
      bv[2]=(_Float16)r0[rr].z; bv[3]=(_Float16)r0[rr].w;
      bv[4]=(_Float16)r1[rr].x; bv[5]=(_Float16)r1[rr].y;
      bv[6]=(_Float16)r1[rr].z; bv[7]=(_Float16)r1[rr].w;
      *(f16x8*)(rhc + ((row * 1024 + lane * 16) ^ ((row & 7) << 4))) = bv;
      float rn = r0[rr].x*r0[rr].x + r0[rr].y*r0[rr].y + r0[rr].z*r0[rr].z + r0[rr].w*r0[rr].w
               + r1[rr].x*r1[rr].x + r1[rr].y*r1[rr].y + r1[rr].z*r1[rr].z + r1[rr].w*r1[rr].w;
#pragma unroll
      for (int off = 1; off < 64; off <<= 1) rn += __shfl_xor(rn, off);
      if (lane == 0) rnorm_l[row] = rn;
    }
    __syncthreads();                            // A: rh ready

    // ---- MFMA screen: wave w owns cols w*128..+127; both 32-row tiles;
    //      B fragments reused across row tiles; scores packed fp16 in regs ----
    unsigned psA[4][8], psB[4][8];              // [ct][j]: rows tile0 / tile1
    const int ab0 = l31 * 1024 + hs * 16;
    const int asw = (l31 & 7) << 4;
#pragma unroll
    for (int p = 0; p < 2; ++p) {
      const int ct0 = 2 * p, ct1 = 2 * p + 1;
      const _Float16* bp0 = cbf_q + (size_t)(w * 4 + ct0) * 16384 + hs * 256 + l31 * 8;
      const _Float16* bp1 = cbf_q + (size_t)(w * 4 + ct1) * 16384 + hs * 256 + l31 * 8;
      f32x16 a00, a01, a10, a11;
#pragma unroll
      for (int i = 0; i < 16; ++i) { a00[i]=0.f; a01[i]=0.f; a10[i]=0.f; a11[i]=0.f; }
#pragma unroll 8
      for (int ds = 0; ds < 32; ++ds) {
        f16x8 a0 = *(const f16x8*)(rhc + ((ab0 + ds * 32) ^ asw));
        f16x8 a1 = *(const f16x8*)(rhc + ((ab0 + 32 * 1024 + ds * 32) ^ asw));
        f16x8 b0 = *(const f16x8*)(bp0 + ds * 512);
        f16x8 b1 = *(const f16x8*)(bp1 + ds * 512);
        a00 = __builtin_amdgcn_mfma_f32_32x32x16_f16(a0, b0, a00, 0, 0, 0);
        a01 = __builtin_amdgcn_mfma_f32_32x32x16_f16(a0, b1, a01, 0, 0, 0);
        a10 = __builtin_amdgcn_mfma_f32_32x32x16_f16(a1, b0, a10, 0, 0, 0);
        a11 = __builtin_amdgcn_mfma_f32_32x32x16_f16(a1, b1, a11, 0, 0, 0);
      }
      const float cn0 = cbn_q[w * 128 + ct0 * 32 + l31];
      const float cn1 = cbn_q[w * 128 + ct1 * 32 + l31];
#pragma unroll
      for (int j = 0; j < 8; ++j) {
        psA[ct0][j] = pack2h((_Float16)(cn0 - 2.f * a00[2*j]), (_Float16)(cn0 - 2.f * a00[2*j+1]));
        psA[ct1][j] = pack2h((_Float16)(cn1 - 2.f * a01[2*j]), (_Float16)(cn1 - 2.f * a01[2*j+1]));
        psB[ct0][j] = pack2h((_Float16)(cn0 - 2.f * a10[2*j]), (_Float16)(cn0 - 2.f * a10[2*j+1]));
        psB[ct1][j] = pack2h((_Float16)(cn1 - 2.f * a11[2*j]), (_Float16)(cn1 - 2.f * a11[2*j+1]));
      }
    }

    // ---- per-row packed (score,col) argmin across this wave's 128 cols ----
#pragma unroll
    for (int rt = 0; rt < 2; ++rt) {
      unsigned pk[16];
#pragma unroll
      for (int i = 0; i < 16; ++i) {
        pk[i] = 0xFFFFFFFFu;
#pragma unroll
        for (int ct = 0; ct < 4; ++ct) {
          unsigned col = (unsigned)(w * 128 + ct * 32 + l31);
          unsigned u = ((rt == 0 ? psA[ct][i >> 1] : psB[ct][i >> 1]) >> ((i & 1) * 16)) & 0xFFFFu;
          unsigned key = (u & 0x8000u) ? (u ^ 0xFFFFu) : (u | 0x8000u);
          unsigned pkc = (key << 10) | col;
          if (pkc < pk[i]) pk[i] = pkc;
        }
#pragma unroll
        for (int off = 1; off <= 16; off <<= 1) {
          unsigned t = __shfl_xor(pk[i], off);
          if (t < pk[i]) pk[i] = t;
        }
      }
      if (l31 == 0) {
#pragma unroll
        for (int i = 0; i < 16; ++i) {
          int rit = rt * 32 + (i & 3) + 8 * (i >> 2) + 4 * hs;
          redB[rit * 8 + w] = pk[i];
        }
      }
    }
    __syncthreads();                            // B: redB ready

    if (tid < 64) {
      unsigned mb = redB[tid * 8];
#pragma unroll
      for (int j = 1; j < 8; ++j) {
        unsigned v = redB[tid * 8 + j];
        if (v < mb) mb = v;
      }
      unsigned key = (mb >> 10) & 0xFFFFu;
      unsigned ub = (key & 0x8000u) ? (key ^ 0x8000u) : (key ^ 0xFFFFu);
      float mstar = (float)__builtin_bit_cast(_Float16, (unsigned short)ub);
      float rn = sqrtf(rnorm_l[tid]);
      float cm = cmax[qi];
      // certified fp16 window: 2*(2u*2*rn*cm) + pack slack
      thrL[tid] = mstar + 0.005f * rn * cm + 0.001f * fabsf(mstar) + 0.3f;
      rowcount[tid] = 0;
    }
    __syncthreads();                            // C: thr ready

    // ---- candidate scan from register scores ----
#pragma unroll
    for (int rt = 0; rt < 2; ++rt) {
#pragma unroll
      for (int i = 0; i < 16; ++i) {
        int rit = rt * 32 + (i & 3) + 8 * (i >> 2) + 4 * hs;
        float t = thrL[rit];
#pragma unroll
        for (int ct = 0; ct < 4; ++ct) {
          unsigned col = (unsigned)(w * 128 + ct * 32 + l31);
          unsigned u = ((rt == 0 ? psA[ct][i >> 1] : psB[ct][i >> 1]) >> ((i & 1) * 16)) & 0xFFFFu;
          float s = (float)__builtin_bit_cast(_Float16, (unsigned short)u);
          if (s <= t) {
            int p = atomicAdd(&rowcount[rit], 1);
            if (p < 32) rowlist[rit * 32 + p] = (unsigned short)col;
          }
        }
      }
    }
    __syncthreads();                            // D: rowlist ready

    // ---- exact f32 rescore + register residual update ----
#pragma unroll
    for (int rr = 0; rr < 8; ++rr) {
      int row = w * 8 + rr;
      int cnt = rowcount[row];
      int total = (cnt > 32) ? Kk : cnt;
      float bs = 3.4028235e38f; int bk = 1 << 30;
      for (int ci2 = 0; ci2 < total; ++ci2) {
        int k = (cnt > 32) ? ci2 : (int)rowlist[row * 32 + ci2];
        const f32x4* crow = (const f32x4*)(cb_q + ((size_t)k << 9)) + lane * 2;
        f32x4 c0 = crow[0], c1 = crow[1];
        float dot = 0.f;
        dot = fmaf(r0[rr].x, c0.x, dot); dot = fmaf(r0[rr].y, c0.y, dot);
        dot = fmaf(r0[rr].z, c0.z, dot); dot = fmaf(r0[rr].w, c0.w, dot);
        dot = fmaf(r1[rr].x, c1.x, dot); dot = fmaf(r1[rr].y, c1.y, dot);
        dot = fmaf(r1[rr].z, c1.z, dot); dot = fmaf(r1[rr].w, c1.w, dot);
#pragma unroll
        for (int off = 1; off < 64; off <<= 1) dot += __shfl_xor(dot, off);
        float sc = cbn_q[k] - 2.f * dot;
        if (sc < bs || (sc == bs && k < bk)) { bs = sc; bk = k; }
      }
      if (lane == 0) idxo[(size_t)qi * NROWS + row0g + row] = (float)bk;
      const f32x4* crow = (const f32x4*)(cb_q + ((size_t)bk << 9)) + lane * 2;
      f32x4 c0 = crow[0], c1 = crow[1];
      r0[rr].x -= c0.x; r0[rr].y -= c0.y; r0[rr].z -= c0.z; r0[rr].w -= c0.w;
      r1[rr].x -= c1.x; r1[rr].y -= c1.y; r1[rr].z -= c1.z; r1[rr].w -= c1.w;
      lsum += r0[rr].x*r0[rr].x + r0[rr].y*r0[rr].y + r0[rr].z*r0[rr].z + r0[rr].w*r0[rr].w
            + r1[rr].x*r1[rr].x + r1[rr].y*r1[rr].y + r1[rr].z*r1[rr].z + r1[rr].w*r1[rr].w;
    }
    __syncthreads();                            // E: step done
  }

  // ---- write quantized_out = x - r_final ----
#pragma unroll
  for (int rr = 0; rr < 8; ++rr) {
    size_t gb = (size_t)(row0g + w * 8 + rr) * Dq + lane * 8;
    f32x4 xv0 = *(const f32x4*)(x + gb), xv1 = *(const f32x4*)(x + gb + 4);
    f32x4 o0, o1;
    o0.x = xv0.x - r0[rr].x; o0.y = xv0.y - r0[rr].y;
    o0.z = xv0.z - r0[rr].z; o0.w = xv0.w - r0[rr].w;
    o1.x = xv1.x - r1[rr].x; o1.y = xv1.y - r1[rr].y;
    o1.z = xv1.z - r1[rr].z; o1.w = xv1.w - r1[rr].w;
    *(f32x4*)(qo + gb) = o0;
    *(f32x4*)(qo + gb + 4) = o1;
  }
#pragma unroll
  for (int off = 1; off < 64; off <<= 1) lsum += __shfl_xor(lsum, off);
  if (lane == 0) atomicAdd(lacc, lsum);
}

// ============ conv1d stride2 SAME via bf16 MFMA + exact GELU ============
__global__ __launch_bounds__(512, 2) void conv_mfma(const float* __restrict__ qo,
                                                    const __bf16* __restrict__ wb,
                                                    float* __restrict__ y) {
  __shared__ char As[259 * 128];                // 259 input rows x 64 ci bf16
  const int tid = threadIdx.x;
  const int w = tid >> 6, lane = tid & 63, l31 = lane & 31, hs = lane >> 5;
  const int rowblk = blockIdx.x, coblk = blockIdx.y;
  const int n = rowblk >> 4;
  const int o0 = (rowblk & 15) * 128;
  const int t0 = 2 * o0 - 1;
  const int c32g = coblk * 8 + w;

  f32x16 acc[4];
#pragma unroll
  for (int rt = 0; rt < 4; ++rt)
#pragma unroll
    for (int i = 0; i < 16; ++i) acc[rt][i] = 0.f;

  for (int ct8 = 0; ct8 < 8; ++ct8) {
    __syncthreads();
    for (int s = tid; s < 2072; s += 512) {
      int irow = s >> 3, cg = s & 7;
      int t = t0 + irow;
      bf16x8 bv;
      if (t >= 0 && t < Tq) {
        const float* src = qo + ((size_t)(n * Tq + t)) * Dq + ct8 * 64 + cg * 8;
        f32x4 v0 = *(const f32x4*)(src), v1 = *(const f32x4*)(src + 4);
        bv[0]=(__bf16)v0.x; bv[1]=(__bf16)v0.y; bv[2]=(__bf16)v0.z; bv[3]=(__bf16)v0.w;
        bv[4]=(__bf16)v1.x; bv[5]=(__bf16)v1.y; bv[6]=(__bf16)v1.z; bv[7]=(__bf16)v1.w;
      } else {
#pragma unroll
        for (int e = 0; e < 8; ++e) bv[e] = (__bf16)0.f;
      }
      *(bf16x8*)(As + ((irow * 128 + cg * 16) ^ (((irow >> 1) & 7) << 4))) = bv;
    }
    __syncthreads();
#pragma unroll
    for (int kw = 0; kw < 5; ++kw) {
#pragma unroll
      for (int ks = 0; ks < 4; ++ks) {
        int s16 = kw * 32 + ct8 * 4 + ks;
        bf16x8 b = *(const bf16x8*)(wb + ((size_t)(s16 * 16 + c32g) * 2 + hs) * 256 + l31 * 8);
#pragma unroll
        for (int rt = 0; rt < 4; ++rt) {
          int ir = 2 * (rt * 32 + l31) + kw;
          bf16x8 a = *(const bf16x8*)(As + ((ir * 128 + ks * 32 + hs * 16) ^ (((ir >> 1) & 7) << 4)));
          acc[rt] = __builtin_amdgcn_mfma_f32_32x32x16_bf16(a, b, acc[rt], 0, 0, 0);
        }
      }
    }
  }
  const int co = coblk * 256 + w * 32 + l31;
#pragma unroll
  for (int rt = 0; rt < 4; ++rt)
#pragma unroll
    for (int i = 0; i < 16; ++i) {
      int orow = rt * 32 + (i & 3) + 8 * (i >> 2) + 4 * hs;
      float v = acc[rt][i];
      float g = 0.5f * v * (1.f + erff(v * 0.70710678118654752f));
      y[((size_t)(n * OWn + o0 + orow)) * Dq + co] = g;
    }
}

__global__ void loss_final(const float* __restrict__ lacc, float* __restrict__ out) {
  out[0] = 0.25f * lacc[0] / 16777216.0f;
}

extern "C" void kernel_launch(void* const* d_in, const int* in_sizes, int n_in,
                              void* d_out, int out_size, void* d_ws, size_t ws_size,
                              hipStream_t stream) {
  const float* x  = (const float*)d_in[0];
  const float* cb = (const float*)d_in[1];
  const float* cw = (const float*)d_in[2];
  float* out = (float*)d_out;
  float* y    = out;
  float* qo   = out + QO_OFF;
  float* idxo = out + IDX_OFF;
  float* losso = out + LOSS_OFF;

  float* fws    = (float*)d_ws;
  float* lacc   = fws;                // 1
  float* cmax   = fws + 8;            // 4
  float* cbnorm = fws + 16;           // 4096
  _Float16* cbf = (_Float16*)((char*)d_ws + (32 << 10));    // 4 MB
  __bf16* wb  = (__bf16*)((char*)d_ws + (8 << 20));         // 2.62 MB

  prep_cb<<<1024, 256, 0, stream>>>(cb, cbnorm, cbf, lacc);
  prep_cmax<<<1, 256, 0, stream>>>(cbnorm, cmax);
  prep_wb<<<640, 256, 0, stream>>>(cw, wb);

  vq_all<<<512, 512, 0, stream>>>(x, qo, cbf, cb, cbnorm, cmax, idxo, lacc);

  conv_mfma<<<dim3(128, 2), 512, 0, stream>>>(qo, wb, y);
  loss_final<<<1, 1, 0, stream>>>(lacc, losso);
}